// Round 3
// baseline (5686.581 us; speedup 1.0000x reference)
//
#include <hip/hip_runtime.h>

#define L_ 6
#define E_ 768
#define H_ 12
#define T_ 1024
#define B_ 4
#define V_ 256
#define M_ (B_*T_)      // 4096 tokens
#define E4_ (4*E_)      // 3072
#define QKVN (3*E_)     // 2304

typedef __bf16 bf16;
typedef __bf16 bf16x8 __attribute__((ext_vector_type(8)));
typedef float f32x4 __attribute__((ext_vector_type(4)));

#define GF_GELU     1
#define GF_RES      2
#define GF_OUTF32   4
#define GF_OUTDYN   8
#define GF_BIAS_EXT 16

// dual-mode scalar load of a "float" input that may be fp32 or bf16
__device__ __forceinline__ float ldf(const void* p, size_t i, int f32m) {
    return f32m ? ((const float*)p)[i] : (float)((const bf16*)p)[i];
}

// ---------------- dtype probe: dm[0]=inputs-are-fp32, dm[1]=idx-is-int64 --------
// fp32 data read as bf16 at even halfword indices = low mantissa halves ->
// ~47% have |v|>100 (incl. inf/NaN). Real bf16 N(0,0.02) data: none do.
// int64 idx (values<256): odd int32 words all zero. int32 idx: ~99.6% nonzero.
__global__ __launch_bounds__(256) void k_probe(const void* __restrict__ tok,
    const void* __restrict__ idxp, int* __restrict__ dm)
{
    __shared__ int sc1, sc2;
    if (threadIdx.x == 0) { sc1 = 0; sc2 = 0; }
    __syncthreads();
    const bf16* tb = (const bf16*)tok;
    int c1 = 0;
    for (int i = threadIdx.x; i < 4096; i += 256) {
        float v = (float)tb[2 * i];
        if (!(fabsf(v) < 100.f)) c1++;          // NaN lands here too
    }
    const int* ip = (const int*)idxp;
    int c2 = 0;
    for (int i = threadIdx.x; i < 1024; i += 256)
        if (ip[2 * i + 1] != 0) c2++;
    atomicAdd(&sc1, c1);
    atomicAdd(&sc2, c2);
    __syncthreads();
    if (threadIdx.x == 0) { dm[0] = (sc1 > 400) ? 1 : 0; dm[1] = (sc2 < 100) ? 1 : 0; }
}

// ---------------- embedding: x = tok_emb[idx] + pos_emb ----------------
__global__ __launch_bounds__(256) void k_embed(const void* __restrict__ idxp,
    const void* __restrict__ tok, const void* __restrict__ pos,
    float* __restrict__ x, const int* __restrict__ dm)
{
    int f32m = dm[0], i64m = dm[1];
    int bt = blockIdx.x;
    int t  = bt & (T_ - 1);
    int id = i64m ? ((const int*)idxp)[2 * bt] : ((const int*)idxp)[bt]; // LE low word
    float* xo = x + (size_t)bt * E_;
    for (int e = threadIdx.x; e < E_; e += 256)
        xo[e] = ldf(tok, (size_t)id * E_ + e, f32m) + ldf(pos, (size_t)t * E_ + e, f32m);
}

// ---------------- layernorm: fp32 x -> bf16 out (w,b external, +elem offset) ----
__global__ __launch_bounds__(256) void k_ln(const float* __restrict__ x,
    const void* __restrict__ w, const void* __restrict__ b, size_t wboff,
    bf16* __restrict__ out, const int* __restrict__ dm)
{
    int f32m = dm[0];
    int row = blockIdx.x;
    int tid = threadIdx.x;
    const float* xr = x + (size_t)row * E_;
    float v0 = xr[tid], v1 = xr[tid + 256], v2 = xr[tid + 512];
    float s  = v0 + v1 + v2;
    float s2 = v0*v0 + v1*v1 + v2*v2;
    for (int off = 32; off; off >>= 1) {
        s  += __shfl_xor(s,  off);
        s2 += __shfl_xor(s2, off);
    }
    __shared__ float ls[4], ls2[4];
    int wave = tid >> 6;
    if ((tid & 63) == 0) { ls[wave] = s; ls2[wave] = s2; }
    __syncthreads();
    s  = ls[0] + ls[1] + ls[2] + ls[3];
    s2 = ls2[0] + ls2[1] + ls2[2] + ls2[3];
    float mu  = s * (1.0f / E_);
    float var = s2 * (1.0f / E_) - mu * mu;
    float rs  = rsqrtf(var + 1e-5f);
    bf16* o = out + (size_t)row * E_;
    o[tid]       = (bf16)(((v0 - mu) * rs) * ldf(w, wboff + tid,       f32m) + ldf(b, wboff + tid,       f32m));
    o[tid + 256] = (bf16)(((v1 - mu) * rs) * ldf(w, wboff + tid + 256, f32m) + ldf(b, wboff + tid + 256, f32m));
    o[tid + 512] = (bf16)(((v2 - mu) * rs) * ldf(w, wboff + tid + 512, f32m) + ldf(b, wboff + tid + 512, f32m));
}

// ---------------- transpose external weight (+elem offset) -> canonical bf16 ----
__global__ __launch_bounds__(256) void k_transpose(const void* __restrict__ in, size_t inoff,
    bf16* __restrict__ out, int R, int C, const int* __restrict__ dm)
{
    int f32m = dm[0];
    __shared__ bf16 tile[32][33];
    int r0 = blockIdx.x * 32, c0 = blockIdx.y * 32;
    int tx = threadIdx.x & 31, ty = threadIdx.x >> 5;   // 32 x 8
    #pragma unroll
    for (int i = 0; i < 4; i++)
        tile[ty + 8*i][tx] = (bf16)ldf(in, inoff + (size_t)(r0 + ty + 8*i) * C + (c0 + tx), f32m);
    __syncthreads();
    #pragma unroll
    for (int i = 0; i < 4; i++)
        out[(size_t)(c0 + ty + 8*i) * R + (r0 + tx)] = tile[tx][ty + 8*i];
}

// ---------------- concat 3 external bias vectors (+elem offset) -> bf16 ---------
__global__ __launch_bounds__(256) void k_cat3(const void* __restrict__ a,
    const void* __restrict__ b, const void* __restrict__ c, size_t voff,
    bf16* __restrict__ o, const int* __restrict__ dm)
{
    int f32m = dm[0];
    int i = blockIdx.x * 256 + threadIdx.x;   // grid covers QKVN exactly
    float v = (i < E_) ? ldf(a, voff + i, f32m)
            : ((i < 2*E_) ? ldf(b, voff + i - E_, f32m) : ldf(c, voff + i - 2*E_, f32m));
    o[i] = (bf16)v;
}

// ---------------- GEMM: C[M,N] = A[M,K] @ BT[N,K]^T + bias, epilogue flags ------
// 128x128 tile, BK=64, 4 waves (2x2), each wave 64x64 via 4x4 mfma_16x16x32_bf16.
// A and BT are always internal canonical bf16; bias may be external (GF_BIAS_EXT).
__global__ __launch_bounds__(256) void k_gemm(const bf16* __restrict__ A,
    const bf16* __restrict__ BT, const void* __restrict__ bias, size_t boff,
    const float* __restrict__ res, void* __restrict__ outp,
    int M, int N, int K, int flags, const int* __restrict__ dm)
{
    int f32m = dm[0];
    __shared__ __attribute__((aligned(16))) bf16 As[128][72];
    __shared__ __attribute__((aligned(16))) bf16 Bs[128][72];
    int tid = threadIdx.x;
    int bn0 = blockIdx.x * 128, bm0 = blockIdx.y * 128;
    int wave = tid >> 6, lane = tid & 63, quad = lane >> 4, l16 = lane & 15;
    int wr = wave >> 1, wc = wave & 1;

    f32x4 acc[4][4];
    #pragma unroll
    for (int i = 0; i < 4; i++)
        #pragma unroll
        for (int j = 0; j < 4; j++)
            acc[i][j] = (f32x4){0.f, 0.f, 0.f, 0.f};

    for (int k0 = 0; k0 < K; k0 += 64) {
        #pragma unroll
        for (int i = 0; i < 4; i++) {
            int li = i * 256 + tid;
            int row = li >> 3;
            int col = (li & 7) * 8;
            *(bf16x8*)&As[row][col] = *(const bf16x8*)(A  + (size_t)(bm0 + row) * K + k0 + col);
            *(bf16x8*)&Bs[row][col] = *(const bf16x8*)(BT + (size_t)(bn0 + row) * K + k0 + col);
        }
        __syncthreads();
        #pragma unroll
        for (int ks = 0; ks < 2; ks++) {
            bf16x8 af[4], bfr[4];
            #pragma unroll
            for (int mi = 0; mi < 4; mi++)
                af[mi] = *(const bf16x8*)&As[wr*64 + mi*16 + l16][ks*32 + quad*8];
            #pragma unroll
            for (int ni = 0; ni < 4; ni++)
                bfr[ni] = *(const bf16x8*)&Bs[wc*64 + ni*16 + l16][ks*32 + quad*8];
            #pragma unroll
            for (int mi = 0; mi < 4; mi++)
                #pragma unroll
                for (int ni = 0; ni < 4; ni++)
                    acc[mi][ni] = __builtin_amdgcn_mfma_f32_16x16x32_bf16(af[mi], bfr[ni], acc[mi][ni], 0, 0, 0);
        }
        __syncthreads();
    }

    // epilogue: D row = base + 4*quad + reg, col = base + l16 (m89-verified C/D layout)
    #pragma unroll
    for (int mi = 0; mi < 4; mi++) {
        #pragma unroll
        for (int ni = 0; ni < 4; ni++) {
            int col = bn0 + wc*64 + ni*16 + l16;
            float bv = 0.f;
            if (bias) bv = (flags & GF_BIAS_EXT) ? ldf(bias, boff + col, f32m)
                                                 : (float)((const bf16*)bias)[col];
            #pragma unroll
            for (int r = 0; r < 4; r++) {
                int row = bm0 + wr*64 + mi*16 + quad*4 + r;
                float val = acc[mi][ni][r] + bv;
                if (flags & GF_GELU) val = 0.5f * val * (1.f + erff(val * 0.70710678118f));
                if (flags & GF_RES)  val += res[(size_t)row * N + col];
                size_t oidx = (size_t)row * N + col;
                if (flags & GF_OUTF32)      ((float*)outp)[oidx] = val;
                else if (flags & GF_OUTDYN) {
                    if (f32m) ((float*)outp)[oidx] = val;
                    else      ((bf16*)outp)[oidx]  = (bf16)val;
                }
                else                        ((bf16*)outp)[oidx]  = (bf16)val;
            }
        }
    }
}

// ---------------- simple attention (kept for bisection): one wave per (b,h,t) ----
__global__ __launch_bounds__(256) void k_attn_simple(const bf16* __restrict__ qkv,
                                                     bf16* __restrict__ y)
{
    __shared__ float sc[4][T_];     // per-wave score row
    __shared__ float qs[4][64];     // per-wave q vector
    int wid = threadIdx.x >> 6, lane = threadIdx.x & 63;
    int w  = blockIdx.x * 4 + wid;          // global wave id in [0, B*H*T)
    int t  = w & (T_ - 1);
    int hb = w >> 10;                        // T_ == 1024
    int h  = hb % H_;
    int b  = hb / H_;

    const bf16* qp    = qkv + (size_t)(b * T_ + t) * QKVN + h * 64;
    const bf16* kbase = qkv + (size_t)b * T_ * QKVN + E_     + h * 64;
    const bf16* vbase = qkv + (size_t)b * T_ * QKVN + 2 * E_ + h * 64;

    qs[wid][lane] = (float)qp[lane];
    __syncthreads();

    int ns = t + 1;                          // causal: s in [0, t]
    float m = -3.0e38f;
    for (int s = lane; s < ns; s += 64) {
        const bf16* kp = kbase + (size_t)s * QKVN;
        float acc = 0.f;
        #pragma unroll
        for (int d = 0; d < 64; d++) acc += qs[wid][d] * (float)kp[d];
        acc *= 0.125f;                       // 1/sqrt(64)
        sc[wid][s] = acc;
        m = fmaxf(m, acc);
    }
    #pragma unroll
    for (int off = 32; off; off >>= 1) m = fmaxf(m, __shfl_xor(m, off));
    float l = 0.f;
    for (int s = lane; s < ns; s += 64) {
        float p = expf(sc[wid][s] - m);
        sc[wid][s] = p;
        l += p;
    }
    #pragma unroll
    for (int off = 32; off; off >>= 1) l += __shfl_xor(l, off);
    __syncthreads();                         // cross-lane sc reads below

    float o = 0.f;
    for (int s = 0; s < ns; s++)
        o += sc[wid][s] * (float)vbase[(size_t)s * QKVN + lane];
    o /= l;
    y[(size_t)(b * T_ + t) * E_ + h * 64 + lane] = (bf16)o;
}

// ---------------- host-side orchestration ----------------
extern "C" void kernel_launch(void* const* d_in, const int* in_sizes, int n_in,
                              void* d_out, int out_size, void* d_ws, size_t ws_size,
                              hipStream_t stream)
{
    const void* idx     = d_in[0];
    const void* tok_emb = d_in[1];
    const void* pos_emb = d_in[2];
    const void* ln1_w   = d_in[3];
    const void* ln1_b   = d_in[4];
    const void* Wq      = d_in[5];
    const void* bq      = d_in[6];
    const void* Wk      = d_in[7];
    const void* bk      = d_in[8];
    const void* Wv      = d_in[9];
    const void* bv      = d_in[10];
    const void* Wp      = d_in[11];
    const void* bp      = d_in[12];
    const void* ln2_w   = d_in[13];
    const void* ln2_b   = d_in[14];
    const void* W1      = d_in[15];
    const void* b1      = d_in[16];
    const void* W2      = d_in[17];
    const void* b2      = d_in[18];
    const void* lnf_w   = d_in[19];
    const void* lnf_b   = d_in[20];
    const void* lm_head = d_in[21];

    char* base = (char*)d_ws;
    size_t off = 0;
    auto nxt = [&](size_t bytes) -> void* {
        void* p = base + off;
        off += (bytes + 255) & ~(size_t)255;
        return p;
    };
    int*   dm   = (int*)  nxt(256);                     // dtype-mode flags
    float* x    = (float*)nxt((size_t)M_ * E_ * 4);     // fp32 residual stream
    bf16*  h    = (bf16*) nxt((size_t)M_ * E_ * 2);     // LN output
    bf16*  qkv  = (bf16*) nxt((size_t)M_ * QKVN * 2);
    bf16*  yb   = (bf16*) nxt((size_t)M_ * E_ * 2);     // attention output
    bf16*  mbuf = (bf16*) nxt((size_t)M_ * E4_ * 2);    // MLP intermediate
    bf16*  wt   = (bf16*) nxt((size_t)E4_ * E_ * 2);    // transposed-weight scratch (reused)
    bf16*  bcat = (bf16*) nxt((size_t)QKVN * 2);
    (void)ws_size; (void)in_sizes; (void)n_in; (void)out_size;

    k_probe<<<1, 256, 0, stream>>>(tok_emb, idx, dm);
    k_embed<<<M_, 256, 0, stream>>>(idx, tok_emb, pos_emb, x, dm);

    for (int l = 0; l < L_; l++) {
        size_t woE  = (size_t)l * E_ * E_;     // element offset into [L,E,E]
        size_t voE  = (size_t)l * E_;          // element offset into [L,E]
        size_t woW1 = (size_t)l * E_ * E4_;    // element offset into [L,E,4E]
        size_t voE4 = (size_t)l * E4_;         // element offset into [L,4E]

        k_ln<<<M_, 256, 0, stream>>>(x, ln1_w, ln1_b, voE, h, dm);

        k_transpose<<<dim3(E_/32, E_/32), 256, 0, stream>>>(Wq, woE, wt,                   E_, E_, dm);
        k_transpose<<<dim3(E_/32, E_/32), 256, 0, stream>>>(Wk, woE, wt + (size_t)E_*E_,   E_, E_, dm);
        k_transpose<<<dim3(E_/32, E_/32), 256, 0, stream>>>(Wv, woE, wt + (size_t)2*E_*E_, E_, E_, dm);
        k_cat3<<<QKVN/256, 256, 0, stream>>>(bq, bk, bv, voE, bcat, dm);
        k_gemm<<<dim3(QKVN/128, M_/128), 256, 0, stream>>>(h, wt, bcat, 0, nullptr, qkv, M_, QKVN, E_, 0, dm);

        k_attn_simple<<<(B_*H_*T_)/4, 256, 0, stream>>>(qkv, yb);

        k_transpose<<<dim3(E_/32, E_/32), 256, 0, stream>>>(Wp, woE, wt, E_, E_, dm);
        k_gemm<<<dim3(E_/128, M_/128), 256, 0, stream>>>(yb, wt, bp, voE, x, x, M_, E_, E_, GF_RES | GF_OUTF32 | GF_BIAS_EXT, dm);

        k_ln<<<M_, 256, 0, stream>>>(x, ln2_w, ln2_b, voE, h, dm);

        k_transpose<<<dim3(E_/32, E4_/32), 256, 0, stream>>>(W1, woW1, wt, E_, E4_, dm);
        k_gemm<<<dim3(E4_/128, M_/128), 256, 0, stream>>>(h, wt, b1, voE4, nullptr, mbuf, M_, E4_, E_, GF_GELU | GF_BIAS_EXT, dm);

        k_transpose<<<dim3(E4_/32, E_/32), 256, 0, stream>>>(W2, woW1, wt, E4_, E_, dm);
        k_gemm<<<dim3(E_/128, M_/128), 256, 0, stream>>>(mbuf, wt, b2, voE, x, x, M_, E_, E4_, GF_RES | GF_OUTF32 | GF_BIAS_EXT, dm);
    }

    k_ln<<<M_, 256, 0, stream>>>(x, lnf_w, lnf_b, 0, h, dm);
    k_transpose<<<dim3(E_/32, V_/32), 256, 0, stream>>>(lm_head, 0, wt, E_, V_, dm);
    k_gemm<<<dim3(V_/128, M_/128), 256, 0, stream>>>(h, wt, nullptr, 0, nullptr, d_out, M_, V_, E_, GF_OUTDYN, dm);
}

// Round 4
// 2250.630 us; speedup vs baseline: 2.5267x; 2.5267x over previous
//
#include <hip/hip_runtime.h>

#define L_ 6
#define E_ 768
#define H_ 12
#define T_ 1024
#define B_ 4
#define V_ 256
#define M_ (B_*T_)      // 4096 tokens
#define E4_ (4*E_)      // 3072
#define QKVN (3*E_)     // 2304

typedef __bf16 bf16;
typedef __bf16 bf16x8 __attribute__((ext_vector_type(8)));
typedef float f32x4 __attribute__((ext_vector_type(4)));

#define GF_GELU     1
#define GF_RES      2
#define GF_OUTF32   4
#define GF_OUTDYN   8
#define GF_BIAS_EXT 16

// dual-mode scalar load of a "float" input that may be fp32 or bf16
__device__ __forceinline__ float ldf(const void* p, size_t i, int f32m) {
    return f32m ? ((const float*)p)[i] : (float)((const bf16*)p)[i];
}

// ---------------- dtype probe: dm[0]=inputs-are-fp32, dm[1]=idx-is-int64 --------
__global__ __launch_bounds__(256) void k_probe(const void* __restrict__ tok,
    const void* __restrict__ idxp, int* __restrict__ dm)
{
    __shared__ int sc1, sc2;
    if (threadIdx.x == 0) { sc1 = 0; sc2 = 0; }
    __syncthreads();
    const bf16* tb = (const bf16*)tok;
    int c1 = 0;
    for (int i = threadIdx.x; i < 4096; i += 256) {
        float v = (float)tb[2 * i];
        if (!(fabsf(v) < 100.f)) c1++;          // NaN lands here too
    }
    const int* ip = (const int*)idxp;
    int c2 = 0;
    for (int i = threadIdx.x; i < 1024; i += 256)
        if (ip[2 * i + 1] != 0) c2++;
    atomicAdd(&sc1, c1);
    atomicAdd(&sc2, c2);
    __syncthreads();
    if (threadIdx.x == 0) { dm[0] = (sc1 > 400) ? 1 : 0; dm[1] = (sc2 < 100) ? 1 : 0; }
}

// ---------------- embedding: x = tok_emb[idx] + pos_emb ----------------
__global__ __launch_bounds__(256) void k_embed(const void* __restrict__ idxp,
    const void* __restrict__ tok, const void* __restrict__ pos,
    float* __restrict__ x, const int* __restrict__ dm)
{
    int f32m = dm[0], i64m = dm[1];
    int bt = blockIdx.x;
    int t  = bt & (T_ - 1);
    int id = i64m ? ((const int*)idxp)[2 * bt] : ((const int*)idxp)[bt]; // LE low word
    float* xo = x + (size_t)bt * E_;
    for (int e = threadIdx.x; e < E_; e += 256)
        xo[e] = ldf(tok, (size_t)id * E_ + e, f32m) + ldf(pos, (size_t)t * E_ + e, f32m);
}

// ---------------- layernorm: fp32 x -> bf16 out (w,b external, +elem offset) ----
__global__ __launch_bounds__(256) void k_ln(const float* __restrict__ x,
    const void* __restrict__ w, const void* __restrict__ b, size_t wboff,
    bf16* __restrict__ out, const int* __restrict__ dm)
{
    int f32m = dm[0];
    int row = blockIdx.x;
    int tid = threadIdx.x;
    const float* xr = x + (size_t)row * E_;
    float v0 = xr[tid], v1 = xr[tid + 256], v2 = xr[tid + 512];
    float s  = v0 + v1 + v2;
    float s2 = v0*v0 + v1*v1 + v2*v2;
    for (int off = 32; off; off >>= 1) {
        s  += __shfl_xor(s,  off);
        s2 += __shfl_xor(s2, off);
    }
    __shared__ float ls[4], ls2[4];
    int wave = tid >> 6;
    if ((tid & 63) == 0) { ls[wave] = s; ls2[wave] = s2; }
    __syncthreads();
    s  = ls[0] + ls[1] + ls[2] + ls[3];
    s2 = ls2[0] + ls2[1] + ls2[2] + ls2[3];
    float mu  = s * (1.0f / E_);
    float var = s2 * (1.0f / E_) - mu * mu;
    float rs  = rsqrtf(var + 1e-5f);
    bf16* o = out + (size_t)row * E_;
    o[tid]       = (bf16)(((v0 - mu) * rs) * ldf(w, wboff + tid,       f32m) + ldf(b, wboff + tid,       f32m));
    o[tid + 256] = (bf16)(((v1 - mu) * rs) * ldf(w, wboff + tid + 256, f32m) + ldf(b, wboff + tid + 256, f32m));
    o[tid + 512] = (bf16)(((v2 - mu) * rs) * ldf(w, wboff + tid + 512, f32m) + ldf(b, wboff + tid + 512, f32m));
}

// ---------------- transpose external weight (+elem offset) -> canonical bf16 ----
__global__ __launch_bounds__(256) void k_transpose(const void* __restrict__ in, size_t inoff,
    bf16* __restrict__ out, int R, int C, const int* __restrict__ dm)
{
    int f32m = dm[0];
    __shared__ bf16 tile[32][33];
    int r0 = blockIdx.x * 32, c0 = blockIdx.y * 32;
    int tx = threadIdx.x & 31, ty = threadIdx.x >> 5;   // 32 x 8
    #pragma unroll
    for (int i = 0; i < 4; i++)
        tile[ty + 8*i][tx] = (bf16)ldf(in, inoff + (size_t)(r0 + ty + 8*i) * C + (c0 + tx), f32m);
    __syncthreads();
    #pragma unroll
    for (int i = 0; i < 4; i++)
        out[(size_t)(c0 + ty + 8*i) * R + (r0 + tx)] = tile[tx][ty + 8*i];
}

// ---------------- concat 3 external bias vectors (+elem offset) -> bf16 ---------
__global__ __launch_bounds__(256) void k_cat3(const void* __restrict__ a,
    const void* __restrict__ b, const void* __restrict__ c, size_t voff,
    bf16* __restrict__ o, const int* __restrict__ dm)
{
    int f32m = dm[0];
    int i = blockIdx.x * 256 + threadIdx.x;   // grid covers QKVN exactly
    float v = (i < E_) ? ldf(a, voff + i, f32m)
            : ((i < 2*E_) ? ldf(b, voff + i - E_, f32m) : ldf(c, voff + i - 2*E_, f32m));
    o[i] = (bf16)v;
}

// ---------------- GEMM: C[M,N] = A[M,K] @ BT[N,K]^T + bias, epilogue flags ------
// 128x128 tile, BK=64, 4 waves (2x2), each wave 64x64 via 4x4 mfma_16x16x32_bf16.
__global__ __launch_bounds__(256) void k_gemm(const bf16* __restrict__ A,
    const bf16* __restrict__ BT, const void* __restrict__ bias, size_t boff,
    const float* __restrict__ res, void* __restrict__ outp,
    int M, int N, int K, int flags, const int* __restrict__ dm)
{
    int f32m = dm[0];
    __shared__ __attribute__((aligned(16))) bf16 As[128][72];
    __shared__ __attribute__((aligned(16))) bf16 Bs[128][72];
    int tid = threadIdx.x;
    int bn0 = blockIdx.x * 128, bm0 = blockIdx.y * 128;
    int wave = tid >> 6, lane = tid & 63, quad = lane >> 4, l16 = lane & 15;
    int wr = wave >> 1, wc = wave & 1;

    f32x4 acc[4][4];
    #pragma unroll
    for (int i = 0; i < 4; i++)
        #pragma unroll
        for (int j = 0; j < 4; j++)
            acc[i][j] = (f32x4){0.f, 0.f, 0.f, 0.f};

    for (int k0 = 0; k0 < K; k0 += 64) {
        #pragma unroll
        for (int i = 0; i < 4; i++) {
            int li = i * 256 + tid;
            int row = li >> 3;
            int col = (li & 7) * 8;
            *(bf16x8*)&As[row][col] = *(const bf16x8*)(A  + (size_t)(bm0 + row) * K + k0 + col);
            *(bf16x8*)&Bs[row][col] = *(const bf16x8*)(BT + (size_t)(bn0 + row) * K + k0 + col);
        }
        __syncthreads();
        #pragma unroll
        for (int ks = 0; ks < 2; ks++) {
            bf16x8 af[4], bfr[4];
            #pragma unroll
            for (int mi = 0; mi < 4; mi++)
                af[mi] = *(const bf16x8*)&As[wr*64 + mi*16 + l16][ks*32 + quad*8];
            #pragma unroll
            for (int ni = 0; ni < 4; ni++)
                bfr[ni] = *(const bf16x8*)&Bs[wc*64 + ni*16 + l16][ks*32 + quad*8];
            #pragma unroll
            for (int mi = 0; mi < 4; mi++)
                #pragma unroll
                for (int ni = 0; ni < 4; ni++)
                    acc[mi][ni] = __builtin_amdgcn_mfma_f32_16x16x32_bf16(af[mi], bfr[ni], acc[mi][ni], 0, 0, 0);
        }
        __syncthreads();
    }

    // epilogue: D row = base + 4*quad + reg, col = base + l16 (m89-verified C/D layout)
    #pragma unroll
    for (int mi = 0; mi < 4; mi++) {
        #pragma unroll
        for (int ni = 0; ni < 4; ni++) {
            int col = bn0 + wc*64 + ni*16 + l16;
            float bv = 0.f;
            if (bias) bv = (flags & GF_BIAS_EXT) ? ldf(bias, boff + col, f32m)
                                                 : (float)((const bf16*)bias)[col];
            #pragma unroll
            for (int r = 0; r < 4; r++) {
                int row = bm0 + wr*64 + mi*16 + quad*4 + r;
                float val = acc[mi][ni][r] + bv;
                if (flags & GF_GELU) val = 0.5f * val * (1.f + erff(val * 0.70710678118f));
                if (flags & GF_RES)  val += res[(size_t)row * N + col];
                size_t oidx = (size_t)row * N + col;
                if (flags & GF_OUTF32)      ((float*)outp)[oidx] = val;
                else if (flags & GF_OUTDYN) {
                    if (f32m) ((float*)outp)[oidx] = val;
                    else      ((bf16*)outp)[oidx]  = (bf16)val;
                }
                else                        ((bf16*)outp)[oidx]  = (bf16)val;
            }
        }
    }
}

// ---------------- MFMA flash attention: qkv[M][2304] -> y[M][768] (bf16) --------
// block = (64 q-rows, head h, batch b); 4 waves x 16 q-rows; s-tiles of 64.
__global__ __launch_bounds__(256) void k_attn(const bf16* __restrict__ qkv, bf16* __restrict__ y)
{
    int qt0 = blockIdx.x * 64;
    int h = blockIdx.y, b = blockIdx.z;
    int tid = threadIdx.x, wave = tid >> 6, lane = tid & 63, quad = lane >> 4, l16 = lane & 15;

    const bf16* qb = qkv + (size_t)b * T_ * QKVN + h * 64;
    const bf16* kb = qb + E_;
    const bf16* vb = qb + 2 * E_;

    __shared__ __attribute__((aligned(16))) bf16 Ks[64][72];
    __shared__ __attribute__((aligned(16))) bf16 Vt[64][72];       // Vt[d][s]
    __shared__ __attribute__((aligned(16))) bf16 Ps[4][16][72];    // per-wave P tile

    // Q fragments (loop-invariant): A[m=l16][k=8*quad+j], two 32-wide k-steps
    bf16x8 qf[2];
    int qrow = qt0 + wave * 16 + l16;
    #pragma unroll
    for (int ks = 0; ks < 2; ks++)
        qf[ks] = *(const bf16x8*)(qb + (size_t)qrow * QKVN + ks*32 + quad*8);

    f32x4 Oacc[4];
    #pragma unroll
    for (int i = 0; i < 4; i++) Oacc[i] = (f32x4){0.f, 0.f, 0.f, 0.f};
    float mrow[4] = {-3.0e38f, -3.0e38f, -3.0e38f, -3.0e38f};
    float lrow[4] = {0.f, 0.f, 0.f, 0.f};

    int ntiles = blockIdx.x + 1;              // causal: s-tiles 0..qtile
    for (int st = 0; st < ntiles; st++) {
        int s0 = st * 64;
        // stage K straight, V transposed
        #pragma unroll
        for (int i = 0; i < 2; i++) {
            int li = i * 256 + tid;
            int row = li >> 3;
            int col = (li & 7) * 8;
            *(bf16x8*)&Ks[row][col] = *(const bf16x8*)(kb + (size_t)(s0 + row) * QKVN + col);
            bf16x8 vv = *(const bf16x8*)(vb + (size_t)(s0 + row) * QKVN + col);
            #pragma unroll
            for (int j = 0; j < 8; j++) Vt[col + j][row] = vv[j];
        }
        __syncthreads();

        // S = Q K^T  (K rows already give the B^T fragment layout)
        f32x4 S[4];
        #pragma unroll
        for (int i = 0; i < 4; i++) S[i] = (f32x4){0.f, 0.f, 0.f, 0.f};
        #pragma unroll
        for (int ks = 0; ks < 2; ks++)
            #pragma unroll
            for (int ni = 0; ni < 4; ni++) {
                bf16x8 kf = *(const bf16x8*)&Ks[ni*16 + l16][ks*32 + quad*8];
                S[ni] = __builtin_amdgcn_mfma_f32_16x16x32_bf16(qf[ks], kf, S[ni], 0, 0, 0);
            }

        // scale + causal mask (diagonal tile only)
        bool diag = (st == blockIdx.x);
        #pragma unroll
        for (int ni = 0; ni < 4; ni++)
            #pragma unroll
            for (int r = 0; r < 4; r++) {
                float sv = S[ni][r] * 0.125f;
                if (diag) {
                    int scol = s0 + ni*16 + l16;
                    int qr   = qt0 + wave*16 + quad*4 + r;
                    if (scol > qr) sv = -1e30f;
                }
                S[ni][r] = sv;
            }

        // online softmax; row = 4*quad + r lives in lanes quad*16..quad*16+15
        float alpha[4];
        #pragma unroll
        for (int r = 0; r < 4; r++) {
            float tm = fmaxf(fmaxf(S[0][r], S[1][r]), fmaxf(S[2][r], S[3][r]));
            #pragma unroll
            for (int off = 1; off <= 8; off <<= 1) tm = fmaxf(tm, __shfl_xor(tm, off));
            float mnew = fmaxf(mrow[r], tm);
            alpha[r] = expf(mrow[r] - mnew);
            mrow[r] = mnew;
            float rsum = 0.f;
            #pragma unroll
            for (int ni = 0; ni < 4; ni++) {
                float p = expf(S[ni][r] - mnew);
                S[ni][r] = p;
                rsum += p;
            }
            #pragma unroll
            for (int off = 1; off <= 8; off <<= 1) rsum += __shfl_xor(rsum, off);
            lrow[r] = lrow[r] * alpha[r] + rsum;
        }
        #pragma unroll
        for (int ni = 0; ni < 4; ni++)
            #pragma unroll
            for (int r = 0; r < 4; r++) {
                Oacc[ni][r] *= alpha[r];
                Ps[wave][quad*4 + r][ni*16 + l16] = (bf16)S[ni][r];   // C-layout -> LDS
            }
        __syncthreads();   // order P writes before cross-lane A-layout reads

        // O += P @ V   (P re-read in A layout, V^T staged so B frags are contiguous)
        #pragma unroll
        for (int ks = 0; ks < 2; ks++) {
            bf16x8 pf = *(const bf16x8*)&Ps[wave][l16][ks*32 + quad*8];
            #pragma unroll
            for (int ni = 0; ni < 4; ni++) {
                bf16x8 vf = *(const bf16x8*)&Vt[ni*16 + l16][ks*32 + quad*8];
                Oacc[ni] = __builtin_amdgcn_mfma_f32_16x16x32_bf16(pf, vf, Oacc[ni], 0, 0, 0);
            }
        }
        __syncthreads();   // before restaging K/V
    }

    // epilogue: O /= l, write y[token][h*64 + d]
    #pragma unroll
    for (int ni = 0; ni < 4; ni++)
        #pragma unroll
        for (int r = 0; r < 4; r++) {
            int row = qt0 + wave*16 + quad*4 + r;
            float ov = Oacc[ni][r] / lrow[r];
            y[(size_t)(b * T_ + row) * E_ + h*64 + ni*16 + l16] = (bf16)ov;
        }
}

// ---------------- host-side orchestration ----------------
extern "C" void kernel_launch(void* const* d_in, const int* in_sizes, int n_in,
                              void* d_out, int out_size, void* d_ws, size_t ws_size,
                              hipStream_t stream)
{
    const void* idx     = d_in[0];
    const void* tok_emb = d_in[1];
    const void* pos_emb = d_in[2];
    const void* ln1_w   = d_in[3];
    const void* ln1_b   = d_in[4];
    const void* Wq      = d_in[5];
    const void* bq      = d_in[6];
    const void* Wk      = d_in[7];
    const void* bk      = d_in[8];
    const void* Wv      = d_in[9];
    const void* bv      = d_in[10];
    const void* Wp      = d_in[11];
    const void* bp      = d_in[12];
    const void* ln2_w   = d_in[13];
    const void* ln2_b   = d_in[14];
    const void* W1      = d_in[15];
    const void* b1      = d_in[16];
    const void* W2      = d_in[17];
    const void* b2      = d_in[18];
    const void* lnf_w   = d_in[19];
    const void* lnf_b   = d_in[20];
    const void* lm_head = d_in[21];

    char* base = (char*)d_ws;
    size_t off = 0;
    auto nxt = [&](size_t bytes) -> void* {
        void* p = base + off;
        off += (bytes + 255) & ~(size_t)255;
        return p;
    };
    int*   dm   = (int*)  nxt(256);                     // dtype-mode flags
    float* x    = (float*)nxt((size_t)M_ * E_ * 4);     // fp32 residual stream
    bf16*  h    = (bf16*) nxt((size_t)M_ * E_ * 2);     // LN output
    bf16*  qkv  = (bf16*) nxt((size_t)M_ * QKVN * 2);
    bf16*  yb   = (bf16*) nxt((size_t)M_ * E_ * 2);     // attention output
    bf16*  mbuf = (bf16*) nxt((size_t)M_ * E4_ * 2);    // MLP intermediate
    bf16*  wt   = (bf16*) nxt((size_t)E4_ * E_ * 2);    // transposed-weight scratch (reused)
    bf16*  bcat = (bf16*) nxt((size_t)QKVN * 2);
    (void)ws_size; (void)in_sizes; (void)n_in; (void)out_size;

    k_probe<<<1, 256, 0, stream>>>(tok_emb, idx, dm);
    k_embed<<<M_, 256, 0, stream>>>(idx, tok_emb, pos_emb, x, dm);

    for (int l = 0; l < L_; l++) {
        size_t woE  = (size_t)l * E_ * E_;     // element offset into [L,E,E]
        size_t voE  = (size_t)l * E_;          // element offset into [L,E]
        size_t woW1 = (size_t)l * E_ * E4_;    // element offset into [L,E,4E]
        size_t voE4 = (size_t)l * E4_;         // element offset into [L,4E]

        k_ln<<<M_, 256, 0, stream>>>(x, ln1_w, ln1_b, voE, h, dm);

        k_transpose<<<dim3(E_/32, E_/32), 256, 0, stream>>>(Wq, woE, wt,                   E_, E_, dm);
        k_transpose<<<dim3(E_/32, E_/32), 256, 0, stream>>>(Wk, woE, wt + (size_t)E_*E_,   E_, E_, dm);
        k_transpose<<<dim3(E_/32, E_/32), 256, 0, stream>>>(Wv, woE, wt + (size_t)2*E_*E_, E_, E_, dm);
        k_cat3<<<QKVN/256, 256, 0, stream>>>(bq, bk, bv, voE, bcat, dm);
        k_gemm<<<dim3(QKVN/128, M_/128), 256, 0, stream>>>(h, wt, bcat, 0, nullptr, qkv, M_, QKVN, E_, 0, dm);

        k_attn<<<dim3(T_/64, H_, B_), 256, 0, stream>>>(qkv, yb);

        k_transpose<<<dim3(E_/32, E_/32), 256, 0, stream>>>(Wp, woE, wt, E_, E_, dm);
        k_gemm<<<dim3(E_/128, M_/128), 256, 0, stream>>>(yb, wt, bp, voE, x, x, M_, E_, E_, GF_RES | GF_OUTF32 | GF_BIAS_EXT, dm);

        k_ln<<<M_, 256, 0, stream>>>(x, ln2_w, ln2_b, voE, h, dm);

        k_transpose<<<dim3(E_/32, E4_/32), 256, 0, stream>>>(W1, woW1, wt, E_, E4_, dm);
        k_gemm<<<dim3(E4_/128, M_/128), 256, 0, stream>>>(h, wt, b1, voE4, nullptr, mbuf, M_, E4_, E_, GF_GELU | GF_BIAS_EXT, dm);

        k_transpose<<<dim3(E4_/32, E_/32), 256, 0, stream>>>(W2, woW1, wt, E4_, E_, dm);
        k_gemm<<<dim3(E_/128, M_/128), 256, 0, stream>>>(mbuf, wt, b2, voE, x, x, M_, E_, E4_, GF_RES | GF_OUTF32 | GF_BIAS_EXT, dm);
    }

    k_ln<<<M_, 256, 0, stream>>>(x, lnf_w, lnf_b, 0, h, dm);
    k_transpose<<<dim3(E_/32, V_/32), 256, 0, stream>>>(lm_head, 0, wt, E_, V_, dm);
    k_gemm<<<dim3(V_/128, M_/128), 256, 0, stream>>>(h, wt, nullptr, 0, nullptr, d_out, M_, V_, E_, GF_OUTDYN, dm);
}

// Round 5
// 1922.671 us; speedup vs baseline: 2.9576x; 1.1706x over previous
//
#include <hip/hip_runtime.h>

#define L_ 6
#define E_ 768
#define H_ 12
#define T_ 1024
#define B_ 4
#define V_ 256
#define M_ (B_*T_)      // 4096 tokens
#define E4_ (4*E_)      // 3072
#define QKVN (3*E_)     // 2304

typedef __bf16 bf16;
typedef __bf16 bf16x8 __attribute__((ext_vector_type(8)));
typedef float f32x4 __attribute__((ext_vector_type(4)));

#define GF_GELU     1
#define GF_RES      2
#define GF_OUTF32   4
#define GF_OUTDYN   8
#define GF_BIAS_EXT 16

// dual-mode scalar load of a "float" input that may be fp32 or bf16
__device__ __forceinline__ float ldf(const void* p, size_t i, int f32m) {
    return f32m ? ((const float*)p)[i] : (float)((const bf16*)p)[i];
}

// async global->LDS, 16B per lane; LDS dest = wave-uniform base + lane*16 (m97/m104)
__device__ __forceinline__ void async_cp16(const void* g, void* l) {
    __builtin_amdgcn_global_load_lds(
        (__attribute__((address_space(1))) void*)g,
        (__attribute__((address_space(3))) void*)l, 16, 0, 0);
}

// ---------------- dtype probe: dm[0]=inputs-are-fp32, dm[1]=idx-is-int64 --------
__global__ __launch_bounds__(256) void k_probe(const void* __restrict__ tok,
    const void* __restrict__ idxp, int* __restrict__ dm)
{
    __shared__ int sc1, sc2;
    if (threadIdx.x == 0) { sc1 = 0; sc2 = 0; }
    __syncthreads();
    const bf16* tb = (const bf16*)tok;
    int c1 = 0;
    for (int i = threadIdx.x; i < 4096; i += 256) {
        float v = (float)tb[2 * i];
        if (!(fabsf(v) < 100.f)) c1++;          // NaN lands here too
    }
    const int* ip = (const int*)idxp;
    int c2 = 0;
    for (int i = threadIdx.x; i < 1024; i += 256)
        if (ip[2 * i + 1] != 0) c2++;
    atomicAdd(&sc1, c1);
    atomicAdd(&sc2, c2);
    __syncthreads();
    if (threadIdx.x == 0) { dm[0] = (sc1 > 400) ? 1 : 0; dm[1] = (sc2 < 100) ? 1 : 0; }
}

// ---------------- embedding: x = tok_emb[idx] + pos_emb ----------------
__global__ __launch_bounds__(256) void k_embed(const void* __restrict__ idxp,
    const void* __restrict__ tok, const void* __restrict__ pos,
    float* __restrict__ x, const int* __restrict__ dm)
{
    int f32m = dm[0], i64m = dm[1];
    int bt = blockIdx.x;
    int t  = bt & (T_ - 1);
    int id = i64m ? ((const int*)idxp)[2 * bt] : ((const int*)idxp)[bt]; // LE low word
    float* xo = x + (size_t)bt * E_;
    for (int e = threadIdx.x; e < E_; e += 256)
        xo[e] = ldf(tok, (size_t)id * E_ + e, f32m) + ldf(pos, (size_t)t * E_ + e, f32m);
}

// ---------------- layernorm: fp32 x -> bf16 out (w,b external, +elem offset) ----
__global__ __launch_bounds__(256) void k_ln(const float* __restrict__ x,
    const void* __restrict__ w, const void* __restrict__ b, size_t wboff,
    bf16* __restrict__ out, const int* __restrict__ dm)
{
    int f32m = dm[0];
    int row = blockIdx.x;
    int tid = threadIdx.x;
    const float* xr = x + (size_t)row * E_;
    float v0 = xr[tid], v1 = xr[tid + 256], v2 = xr[tid + 512];
    float s  = v0 + v1 + v2;
    float s2 = v0*v0 + v1*v1 + v2*v2;
    for (int off = 32; off; off >>= 1) {
        s  += __shfl_xor(s,  off);
        s2 += __shfl_xor(s2, off);
    }
    __shared__ float ls[4], ls2[4];
    int wave = tid >> 6;
    if ((tid & 63) == 0) { ls[wave] = s; ls2[wave] = s2; }
    __syncthreads();
    s  = ls[0] + ls[1] + ls[2] + ls[3];
    s2 = ls2[0] + ls2[1] + ls2[2] + ls2[3];
    float mu  = s * (1.0f / E_);
    float var = s2 * (1.0f / E_) - mu * mu;
    float rs  = rsqrtf(var + 1e-5f);
    bf16* o = out + (size_t)row * E_;
    o[tid]       = (bf16)(((v0 - mu) * rs) * ldf(w, wboff + tid,       f32m) + ldf(b, wboff + tid,       f32m));
    o[tid + 256] = (bf16)(((v1 - mu) * rs) * ldf(w, wboff + tid + 256, f32m) + ldf(b, wboff + tid + 256, f32m));
    o[tid + 512] = (bf16)(((v2 - mu) * rs) * ldf(w, wboff + tid + 512, f32m) + ldf(b, wboff + tid + 512, f32m));
}

// ---------------- transpose external weight (+elem offset) -> canonical bf16 ----
__global__ __launch_bounds__(256) void k_transpose(const void* __restrict__ in, size_t inoff,
    bf16* __restrict__ out, int R, int C, const int* __restrict__ dm)
{
    int f32m = dm[0];
    __shared__ bf16 tile[32][33];
    int r0 = blockIdx.x * 32, c0 = blockIdx.y * 32;
    int tx = threadIdx.x & 31, ty = threadIdx.x >> 5;   // 32 x 8
    #pragma unroll
    for (int i = 0; i < 4; i++)
        tile[ty + 8*i][tx] = (bf16)ldf(in, inoff + (size_t)(r0 + ty + 8*i) * C + (c0 + tx), f32m);
    __syncthreads();
    #pragma unroll
    for (int i = 0; i < 4; i++)
        out[(size_t)(c0 + ty + 8*i) * R + (r0 + tx)] = tile[tx][ty + 8*i];
}

// ---------------- concat 3 external bias vectors (+elem offset) -> bf16 ---------
__global__ __launch_bounds__(256) void k_cat3(const void* __restrict__ a,
    const void* __restrict__ b, const void* __restrict__ c, size_t voff,
    bf16* __restrict__ o, const int* __restrict__ dm)
{
    int f32m = dm[0];
    int i = blockIdx.x * 256 + threadIdx.x;   // grid covers QKVN exactly
    float v = (i < E_) ? ldf(a, voff + i, f32m)
            : ((i < 2*E_) ? ldf(b, voff + i - E_, f32m) : ldf(c, voff + i - 2*E_, f32m));
    o[i] = (bf16)v;
}

// ---------------- GEMM: C[M,N] = A[M,K] @ BT[N,K]^T + bias -----------------------
// 128x128 tile, BK=64, 4 waves (2x2). m97-style: unpadded LDS, global_load_lds
// width=16, XOR swizzle kgs = kg ^ (row&7) folded into the staging SOURCE address
// (bank floor: 8 accesses/bank for wave64 ds_read_b128).
__global__ __launch_bounds__(256) void k_gemm(const bf16* __restrict__ A,
    const bf16* __restrict__ BT, const void* __restrict__ bias, size_t boff,
    const float* __restrict__ res, void* __restrict__ outp,
    int M, int N, int K, int flags, const int* __restrict__ dm)
{
    int f32m = dm[0];
    __shared__ __attribute__((aligned(16))) bf16 As[128 * 64];
    __shared__ __attribute__((aligned(16))) bf16 Bs[128 * 64];
    int tid = threadIdx.x;
    int bn0 = blockIdx.x * 128, bm0 = blockIdx.y * 128;
    int wave = tid >> 6, lane = tid & 63, quad = lane >> 4, l16 = lane & 15;
    int wr = wave >> 1, wc = wave & 1;

    // staging: slot s = wave*256 + i*64 + lane; row = s>>3, kgs = s&7.
    // LDS slot (row,kgs) holds global k-block kg = kgs ^ (row&7).
    // For this thread: row&7 = lane>>3, kgs = lane&7 -> col = 8*((lane&7)^(lane>>3))
    int st_col = 8 * ((lane & 7) ^ (lane >> 3));
    int st_row_base = wave * 32 + (lane >> 3);      // + i*8

    f32x4 acc[4][4];
    #pragma unroll
    for (int i = 0; i < 4; i++)
        #pragma unroll
        for (int j = 0; j < 4; j++)
            acc[i][j] = (f32x4){0.f, 0.f, 0.f, 0.f};

    int sw = l16 & 7;                               // read-side swizzle key
    for (int k0 = 0; k0 < K; k0 += 64) {
        #pragma unroll
        for (int i = 0; i < 4; i++) {
            int row = st_row_base + i * 8;
            const bf16* ga = A  + (size_t)(bm0 + row) * K + k0 + st_col;
            const bf16* gb = BT + (size_t)(bn0 + row) * K + k0 + st_col;
            // wave-uniform LDS base for this instruction's 64 slots
            bf16* la = As + (size_t)(wave * 256 + i * 64) * 8;
            bf16* lb = Bs + (size_t)(wave * 256 + i * 64) * 8;
            async_cp16(ga, la);
            async_cp16(gb, lb);
        }
        __syncthreads();                            // drains vmcnt before barrier
        #pragma unroll
        for (int ks = 0; ks < 2; ks++) {
            bf16x8 af[4], bfr[4];
            #pragma unroll
            for (int mi = 0; mi < 4; mi++) {
                int row = wr*64 + mi*16 + l16;
                int kgs = (4*ks + quad) ^ sw;
                af[mi] = *(const bf16x8*)&As[row*64 + kgs*8];
            }
            #pragma unroll
            for (int ni = 0; ni < 4; ni++) {
                int row = wc*64 + ni*16 + l16;
                int kgs = (4*ks + quad) ^ sw;
                bfr[ni] = *(const bf16x8*)&Bs[row*64 + kgs*8];
            }
            #pragma unroll
            for (int mi = 0; mi < 4; mi++)
                #pragma unroll
                for (int ni = 0; ni < 4; ni++)
                    acc[mi][ni] = __builtin_amdgcn_mfma_f32_16x16x32_bf16(af[mi], bfr[ni], acc[mi][ni], 0, 0, 0);
        }
        __syncthreads();
    }

    // epilogue: D row = base + 4*quad + reg, col = base + l16 (m89-verified)
    #pragma unroll
    for (int mi = 0; mi < 4; mi++) {
        #pragma unroll
        for (int ni = 0; ni < 4; ni++) {
            int col = bn0 + wc*64 + ni*16 + l16;
            float bv = 0.f;
            if (bias) bv = (flags & GF_BIAS_EXT) ? ldf(bias, boff + col, f32m)
                                                 : (float)((const bf16*)bias)[col];
            #pragma unroll
            for (int r = 0; r < 4; r++) {
                int row = bm0 + wr*64 + mi*16 + quad*4 + r;
                float val = acc[mi][ni][r] + bv;
                if (flags & GF_GELU) val = 0.5f * val * (1.f + erff(val * 0.70710678118f));
                if (flags & GF_RES)  val += res[(size_t)row * N + col];
                size_t oidx = (size_t)row * N + col;
                if (flags & GF_OUTF32)      ((float*)outp)[oidx] = val;
                else if (flags & GF_OUTDYN) {
                    if (f32m) ((float*)outp)[oidx] = val;
                    else      ((bf16*)outp)[oidx]  = (bf16)val;
                }
                else                        ((bf16*)outp)[oidx]  = (bf16)val;
            }
        }
    }
}

// ---------------- paired flash attention ----------------------------------------
// Block = (pair xA / xB=15-xA, head, batch): strips of 64 q-rows each; shared K/V
// staging over s-tiles 0..xB; strip A active while st<=xA. Work = 17 units/block,
// perfectly uniform. Vt built via two-step conflict-free transpose.
__device__ __forceinline__ void attn_qk_softmax(
    const bf16x8 qf[2], f32x4 Oacc[4], float mrow[4], float lrow[4],
    const bf16 (*Ks)[72], bf16 (*Ps)[72],
    int wave, int quad, int l16, int s0, int qt0, bool diag)
{
    f32x4 S[4];
    #pragma unroll
    for (int i = 0; i < 4; i++) S[i] = (f32x4){0.f, 0.f, 0.f, 0.f};
    #pragma unroll
    for (int ks = 0; ks < 2; ks++)
        #pragma unroll
        for (int ni = 0; ni < 4; ni++) {
            bf16x8 kf = *(const bf16x8*)&Ks[ni*16 + l16][ks*32 + quad*8];
            S[ni] = __builtin_amdgcn_mfma_f32_16x16x32_bf16(qf[ks], kf, S[ni], 0, 0, 0);
        }
    #pragma unroll
    for (int ni = 0; ni < 4; ni++)
        #pragma unroll
        for (int r = 0; r < 4; r++) {
            float sv = S[ni][r] * 0.125f;
            if (diag) {
                int scol = s0 + ni*16 + l16;
                int qr   = qt0 + wave*16 + quad*4 + r;
                if (scol > qr) sv = -1e30f;
            }
            S[ni][r] = sv;
        }
    #pragma unroll
    for (int r = 0; r < 4; r++) {
        float tm = fmaxf(fmaxf(S[0][r], S[1][r]), fmaxf(S[2][r], S[3][r]));
        #pragma unroll
        for (int off = 1; off <= 8; off <<= 1) tm = fmaxf(tm, __shfl_xor(tm, off));
        float mnew = fmaxf(mrow[r], tm);
        float alpha = expf(mrow[r] - mnew);
        mrow[r] = mnew;
        float rsum = 0.f;
        #pragma unroll
        for (int ni = 0; ni < 4; ni++) {
            float p = expf(S[ni][r] - mnew);
            S[ni][r] = p;
            rsum += p;
        }
        #pragma unroll
        for (int off = 1; off <= 8; off <<= 1) rsum += __shfl_xor(rsum, off);
        lrow[r] = lrow[r] * alpha + rsum;
        #pragma unroll
        for (int ni = 0; ni < 4; ni++) Oacc[ni][r] *= alpha;
        #pragma unroll
        for (int ni = 0; ni < 4; ni++)
            Ps[wave*16 + quad*4 + r][ni*16 + l16] = (bf16)S[ni][r];   // C->LDS
    }
}

__device__ __forceinline__ void attn_pv(
    f32x4 Oacc[4], const bf16 (*Ps)[72], const bf16 (*Vt)[72],
    int wave, int quad, int l16)
{
    #pragma unroll
    for (int ks = 0; ks < 2; ks++) {
        bf16x8 pf = *(const bf16x8*)&Ps[wave*16 + l16][ks*32 + quad*8];
        #pragma unroll
        for (int ni = 0; ni < 4; ni++) {
            bf16x8 vf = *(const bf16x8*)&Vt[ni*16 + l16][ks*32 + quad*8];
            Oacc[ni] = __builtin_amdgcn_mfma_f32_16x16x32_bf16(pf, vf, Oacc[ni], 0, 0, 0);
        }
    }
}

__global__ __launch_bounds__(256) void k_attn(const bf16* __restrict__ qkv, bf16* __restrict__ y)
{
    int xA = blockIdx.x;              // 0..7 (light strip)
    int xB = 15 - xA;                 // 8..15 (heavy strip)
    int qtA = xA * 64, qtB = xB * 64;
    int h = blockIdx.y, b = blockIdx.z;
    int tid = threadIdx.x, wave = tid >> 6, lane = tid & 63, quad = lane >> 4, l16 = lane & 15;

    const bf16* qb = qkv + (size_t)b * T_ * QKVN + h * 64;
    const bf16* kb = qb + E_;
    const bf16* vb = qb + 2 * E_;

    __shared__ __attribute__((aligned(16))) bf16 Ks[64][72];
    __shared__ __attribute__((aligned(16))) bf16 Vt[64][72];   // Vt[d][s]
    __shared__ __attribute__((aligned(16))) bf16 U1[64][72];   // Vs staging, then PsB
    __shared__ __attribute__((aligned(16))) bf16 PsA[64][72];

    bf16x8 qfA[2], qfB[2];
    {
        int qrA = qtA + wave * 16 + l16;
        int qrB = qtB + wave * 16 + l16;
        #pragma unroll
        for (int ks = 0; ks < 2; ks++) {
            qfA[ks] = *(const bf16x8*)(qb + (size_t)qrA * QKVN + ks*32 + quad*8);
            qfB[ks] = *(const bf16x8*)(qb + (size_t)qrB * QKVN + ks*32 + quad*8);
        }
    }

    f32x4 OA[4], OB[4];
    #pragma unroll
    for (int i = 0; i < 4; i++) { OA[i] = (f32x4){0.f,0.f,0.f,0.f}; OB[i] = (f32x4){0.f,0.f,0.f,0.f}; }
    float mA[4] = {-3.0e38f,-3.0e38f,-3.0e38f,-3.0e38f}, lA[4] = {0.f,0.f,0.f,0.f};
    float mB[4] = {-3.0e38f,-3.0e38f,-3.0e38f,-3.0e38f}, lB[4] = {0.f,0.f,0.f,0.f};

    for (int st = 0; st <= xB; st++) {
        int s0 = st * 64;
        bool doA = (st <= xA);
        // stage K rows + V rows (vector, conflict-free)
        #pragma unroll
        for (int i = 0; i < 2; i++) {
            int li = i * 256 + tid;
            int row = li >> 3;
            int col = (li & 7) * 8;
            *(bf16x8*)&Ks[row][col] = *(const bf16x8*)(kb + (size_t)(s0 + row) * QKVN + col);
            *(bf16x8*)&U1[row][col] = *(const bf16x8*)(vb + (size_t)(s0 + row) * QKVN + col);
        }
        __syncthreads();
        // two-step transpose U1(Vs) -> Vt: scalar reads (dword-broadcast), b128 writes
        {
            int d = tid & 63;
            #pragma unroll
            for (int ii = 0; ii < 2; ii++) {
                int sb = (tid >> 6) * 2 + ii;      // 0..7
                bf16x8 tv;
                #pragma unroll
                for (int j = 0; j < 8; j++) tv[j] = U1[sb*8 + j][d];
                *(bf16x8*)&Vt[d][sb*8] = tv;
            }
        }
        __syncthreads();                            // Vs dead; U1 becomes PsB
        attn_qk_softmax(qfB, OB, mB, lB, Ks, U1,  wave, quad, l16, s0, qtB, st == xB);
        if (doA)
            attn_qk_softmax(qfA, OA, mA, lA, Ks, PsA, wave, quad, l16, s0, qtA, st == xA);
        __syncthreads();                            // P visible across lanes
        attn_pv(OB, U1,  Vt, wave, quad, l16);
        if (doA) attn_pv(OA, PsA, Vt, wave, quad, l16);
        __syncthreads();                            // before restaging
    }

    #pragma unroll
    for (int ni = 0; ni < 4; ni++)
        #pragma unroll
        for (int r = 0; r < 4; r++) {
            int rowB = qtB + wave*16 + quad*4 + r;
            int rowA = qtA + wave*16 + quad*4 + r;
            y[(size_t)(b * T_ + rowB) * E_ + h*64 + ni*16 + l16] = (bf16)(OB[ni][r] / lB[r]);
            y[(size_t)(b * T_ + rowA) * E_ + h*64 + ni*16 + l16] = (bf16)(OA[ni][r] / lA[r]);
        }
}

// ---------------- host-side orchestration ----------------
extern "C" void kernel_launch(void* const* d_in, const int* in_sizes, int n_in,
                              void* d_out, int out_size, void* d_ws, size_t ws_size,
                              hipStream_t stream)
{
    const void* idx     = d_in[0];
    const void* tok_emb = d_in[1];
    const void* pos_emb = d_in[2];
    const void* ln1_w   = d_in[3];
    const void* ln1_b   = d_in[4];
    const void* Wq      = d_in[5];
    const void* bq      = d_in[6];
    const void* Wk      = d_in[7];
    const void* bk      = d_in[8];
    const void* Wv      = d_in[9];
    const void* bv      = d_in[10];
    const void* Wp      = d_in[11];
    const void* bp      = d_in[12];
    const void* ln2_w   = d_in[13];
    const void* ln2_b   = d_in[14];
    const void* W1      = d_in[15];
    const void* b1      = d_in[16];
    const void* W2      = d_in[17];
    const void* b2      = d_in[18];
    const void* lnf_w   = d_in[19];
    const void* lnf_b   = d_in[20];
    const void* lm_head = d_in[21];

    char* base = (char*)d_ws;
    size_t off = 0;
    auto nxt = [&](size_t bytes) -> void* {
        void* p = base + off;
        off += (bytes + 255) & ~(size_t)255;
        return p;
    };
    int*   dm   = (int*)  nxt(256);                     // dtype-mode flags
    float* x    = (float*)nxt((size_t)M_ * E_ * 4);     // fp32 residual stream
    bf16*  h    = (bf16*) nxt((size_t)M_ * E_ * 2);     // LN output
    bf16*  qkv  = (bf16*) nxt((size_t)M_ * QKVN * 2);
    bf16*  yb   = (bf16*) nxt((size_t)M_ * E_ * 2);     // attention output
    bf16*  mbuf = (bf16*) nxt((size_t)M_ * E4_ * 2);    // MLP intermediate
    bf16*  wt   = (bf16*) nxt((size_t)E4_ * E_ * 2);    // transposed-weight scratch (reused)
    bf16*  bcat = (bf16*) nxt((size_t)QKVN * 2);
    (void)ws_size; (void)in_sizes; (void)n_in; (void)out_size;

    k_probe<<<1, 256, 0, stream>>>(tok_emb, idx, dm);
    k_embed<<<M_, 256, 0, stream>>>(idx, tok_emb, pos_emb, x, dm);

    for (int l = 0; l < L_; l++) {
        size_t woE  = (size_t)l * E_ * E_;     // element offset into [L,E,E]
        size_t voE  = (size_t)l * E_;          // element offset into [L,E]
        size_t woW1 = (size_t)l * E_ * E4_;    // element offset into [L,E,4E]
        size_t voE4 = (size_t)l * E4_;         // element offset into [L,4E]

        k_ln<<<M_, 256, 0, stream>>>(x, ln1_w, ln1_b, voE, h, dm);

        k_transpose<<<dim3(E_/32, E_/32), 256, 0, stream>>>(Wq, woE, wt,                   E_, E_, dm);
        k_transpose<<<dim3(E_/32, E_/32), 256, 0, stream>>>(Wk, woE, wt + (size_t)E_*E_,   E_, E_, dm);
        k_transpose<<<dim3(E_/32, E_/32), 256, 0, stream>>>(Wv, woE, wt + (size_t)2*E_*E_, E_, E_, dm);
        k_cat3<<<QKVN/256, 256, 0, stream>>>(bq, bk, bv, voE, bcat, dm);
        k_gemm<<<dim3(QKVN/128, M_/128), 256, 0, stream>>>(h, wt, bcat, 0, nullptr, qkv, M_, QKVN, E_, 0, dm);

        k_attn<<<dim3(8, H_, B_), 256, 0, stream>>>(qkv, yb);

        k_transpose<<<dim3(E_/32, E_/32), 256, 0, stream>>>(Wp, woE, wt, E_, E_, dm);
        k_gemm<<<dim3(E_/128, M_/128), 256, 0, stream>>>(yb, wt, bp, voE, x, x, M_, E_, E_, GF_RES | GF_OUTF32 | GF_BIAS_EXT, dm);

        k_ln<<<M_, 256, 0, stream>>>(x, ln2_w, ln2_b, voE, h, dm);

        k_transpose<<<dim3(E_/32, E4_/32), 256, 0, stream>>>(W1, woW1, wt, E_, E4_, dm);
        k_gemm<<<dim3(E4_/128, M_/128), 256, 0, stream>>>(h, wt, b1, voE4, nullptr, mbuf, M_, E4_, E_, GF_GELU | GF_BIAS_EXT, dm);

        k_transpose<<<dim3(E4_/32, E_/32), 256, 0, stream>>>(W2, woW1, wt, E4_, E_, dm);
        k_gemm<<<dim3(E_/128, M_/128), 256, 0, stream>>>(mbuf, wt, b2, voE, x, x, M_, E_, E4_, GF_RES | GF_OUTF32 | GF_BIAS_EXT, dm);
    }

    k_ln<<<M_, 256, 0, stream>>>(x, lnf_w, lnf_b, 0, h, dm);
    k_transpose<<<dim3(E_/32, V_/32), 256, 0, stream>>>(lm_head, 0, wt, E_, V_, dm);
    k_gemm<<<dim3(V_/128, M_/128), 256, 0, stream>>>(h, wt, nullptr, 0, nullptr, d_out, M_, V_, E_, GF_OUTDYN, dm);
}

// Round 6
// 1885.216 us; speedup vs baseline: 3.0164x; 1.0199x over previous
//
#include <hip/hip_runtime.h>

#define L_ 6
#define E_ 768
#define H_ 12
#define T_ 1024
#define B_ 4
#define V_ 256
#define M_ (B_*T_)      // 4096 tokens
#define E4_ (4*E_)      // 3072
#define QKVN (3*E_)     // 2304

typedef __bf16 bf16;
typedef __bf16 bf16x8 __attribute__((ext_vector_type(8)));
typedef float f32x4 __attribute__((ext_vector_type(4)));

#define GF_GELU     1
#define GF_RES      2
#define GF_OUTF32   4
#define GF_OUTDYN   8
#define GF_BIAS_EXT 16

// s_waitcnt with vmcnt(N) + lgkmcnt(0), expcnt don't-care.
// gfx9 simm16: vmcnt[3:0] | expcnt[2:0]<<4 | lgkmcnt[3:0]<<8 | vmcnt[5:4]<<14
#define WAITCNT_VM(N) __builtin_amdgcn_s_waitcnt(0x0070 | ((N)&0xF) | ((((N)>>4)&0x3)<<14))

// dual-mode scalar load of a "float" input that may be fp32 or bf16
__device__ __forceinline__ float ldf(const void* p, size_t i, int f32m) {
    return f32m ? ((const float*)p)[i] : (float)((const bf16*)p)[i];
}

// async global->LDS, 16B per lane; LDS dest = wave-uniform base + lane*16 (m97/m104)
__device__ __forceinline__ void async_cp16(const void* g, void* l) {
    __builtin_amdgcn_global_load_lds(
        (__attribute__((address_space(1))) void*)g,
        (__attribute__((address_space(3))) void*)l, 16, 0, 0);
}

// ---------------- dtype probe: dm[0]=inputs-are-fp32, dm[1]=idx-is-int64 --------
__global__ __launch_bounds__(256) void k_probe(const void* __restrict__ tok,
    const void* __restrict__ idxp, int* __restrict__ dm)
{
    __shared__ int sc1, sc2;
    if (threadIdx.x == 0) { sc1 = 0; sc2 = 0; }
    __syncthreads();
    const bf16* tb = (const bf16*)tok;
    int c1 = 0;
    for (int i = threadIdx.x; i < 4096; i += 256) {
        float v = (float)tb[2 * i];
        if (!(fabsf(v) < 100.f)) c1++;          // NaN lands here too
    }
    const int* ip = (const int*)idxp;
    int c2 = 0;
    for (int i = threadIdx.x; i < 1024; i += 256)
        if (ip[2 * i + 1] != 0) c2++;
    atomicAdd(&sc1, c1);
    atomicAdd(&sc2, c2);
    __syncthreads();
    if (threadIdx.x == 0) { dm[0] = (sc1 > 400) ? 1 : 0; dm[1] = (sc2 < 100) ? 1 : 0; }
}

// ---------------- embedding: x = tok_emb[idx] + pos_emb ----------------
__global__ __launch_bounds__(256) void k_embed(const void* __restrict__ idxp,
    const void* __restrict__ tok, const void* __restrict__ pos,
    float* __restrict__ x, const int* __restrict__ dm)
{
    int f32m = dm[0], i64m = dm[1];
    int bt = blockIdx.x;
    int t  = bt & (T_ - 1);
    int id = i64m ? ((const int*)idxp)[2 * bt] : ((const int*)idxp)[bt]; // LE low word
    float* xo = x + (size_t)bt * E_;
    for (int e = threadIdx.x; e < E_; e += 256)
        xo[e] = ldf(tok, (size_t)id * E_ + e, f32m) + ldf(pos, (size_t)t * E_ + e, f32m);
}

// ---------------- layernorm: fp32 x -> bf16 out (w,b external, +elem offset) ----
__global__ __launch_bounds__(256) void k_ln(const float* __restrict__ x,
    const void* __restrict__ w, const void* __restrict__ b, size_t wboff,
    bf16* __restrict__ out, const int* __restrict__ dm)
{
    int f32m = dm[0];
    int row = blockIdx.x;
    int tid = threadIdx.x;
    const float* xr = x + (size_t)row * E_;
    float v0 = xr[tid], v1 = xr[tid + 256], v2 = xr[tid + 512];
    float s  = v0 + v1 + v2;
    float s2 = v0*v0 + v1*v1 + v2*v2;
    for (int off = 32; off; off >>= 1) {
        s  += __shfl_xor(s,  off);
        s2 += __shfl_xor(s2, off);
    }
    __shared__ float ls[4], ls2[4];
    int wave = tid >> 6;
    if ((tid & 63) == 0) { ls[wave] = s; ls2[wave] = s2; }
    __syncthreads();
    s  = ls[0] + ls[1] + ls[2] + ls[3];
    s2 = ls2[0] + ls2[1] + ls2[2] + ls2[3];
    float mu  = s * (1.0f / E_);
    float var = s2 * (1.0f / E_) - mu * mu;
    float rs  = rsqrtf(var + 1e-5f);
    bf16* o = out + (size_t)row * E_;
    o[tid]       = (bf16)(((v0 - mu) * rs) * ldf(w, wboff + tid,       f32m) + ldf(b, wboff + tid,       f32m));
    o[tid + 256] = (bf16)(((v1 - mu) * rs) * ldf(w, wboff + tid + 256, f32m) + ldf(b, wboff + tid + 256, f32m));
    o[tid + 512] = (bf16)(((v2 - mu) * rs) * ldf(w, wboff + tid + 512, f32m) + ldf(b, wboff + tid + 512, f32m));
}

// ---------------- transpose external weight (+elem offset) -> canonical bf16 ----
__global__ __launch_bounds__(256) void k_transpose(const void* __restrict__ in, size_t inoff,
    bf16* __restrict__ out, int R, int C, const int* __restrict__ dm)
{
    int f32m = dm[0];
    __shared__ bf16 tile[32][33];
    int r0 = blockIdx.x * 32, c0 = blockIdx.y * 32;
    int tx = threadIdx.x & 31, ty = threadIdx.x >> 5;   // 32 x 8
    #pragma unroll
    for (int i = 0; i < 4; i++)
        tile[ty + 8*i][tx] = (bf16)ldf(in, inoff + (size_t)(r0 + ty + 8*i) * C + (c0 + tx), f32m);
    __syncthreads();
    #pragma unroll
    for (int i = 0; i < 4; i++)
        out[(size_t)(c0 + ty + 8*i) * R + (r0 + tx)] = tile[tx][ty + 8*i];
}

// ---------------- concat 3 external bias vectors (+elem offset) -> bf16 ---------
__global__ __launch_bounds__(256) void k_cat3(const void* __restrict__ a,
    const void* __restrict__ b, const void* __restrict__ c, size_t voff,
    bf16* __restrict__ o, const int* __restrict__ dm)
{
    int f32m = dm[0];
    int i = blockIdx.x * 256 + threadIdx.x;   // grid covers QKVN exactly
    float v = (i < E_) ? ldf(a, voff + i, f32m)
            : ((i < 2*E_) ? ldf(b, voff + i - E_, f32m) : ldf(c, voff + i - 2*E_, f32m));
    o[i] = (bf16)v;
}

// ---------------- GEMM: C[M,N] = A[M,K] @ BT[N,K]^T + bias -----------------------
// 128x128 tile, BK=64, 4 waves (2x2). Unpadded LDS, global_load_lds width=16, XOR
// swizzle in the staging source address. DB=true: ping-pong LDS with raw s_barrier
// + s_waitcnt vmcnt(8) so the prefetch for tile k+1 stays in flight across the
// barrier (needed for small grids at ~1 block/CU where no inter-block overlap
// exists; __syncthreads would drain vmcnt(0) and serialize — m97 plateau).
template<bool DB>
__global__ __launch_bounds__(256) void k_gemm_t(const bf16* __restrict__ A,
    const bf16* __restrict__ BT, const void* __restrict__ bias, size_t boff,
    const float* __restrict__ res, void* __restrict__ outp,
    int M, int N, int K, int flags, const int* __restrict__ dm)
{
    int f32m = dm[0];
    __shared__ __attribute__((aligned(16))) bf16 As[(DB ? 2 : 1) * 128 * 64];
    __shared__ __attribute__((aligned(16))) bf16 Bs[(DB ? 2 : 1) * 128 * 64];
    int tid = threadIdx.x;
    int bn0 = blockIdx.x * 128, bm0 = blockIdx.y * 128;
    int wave = tid >> 6, lane = tid & 63, quad = lane >> 4, l16 = lane & 15;
    int wr = wave >> 1, wc = wave & 1;

    // staging: slot s = wave*256 + i*64 + lane; row = s>>3, kgs = s&7.
    // LDS slot (row,kgs) holds global k-block kg = kgs ^ (row&7).
    int st_col = 8 * ((lane & 7) ^ (lane >> 3));
    int st_row_base = wave * 32 + (lane >> 3);      // + i*8

    f32x4 acc[4][4];
    #pragma unroll
    for (int i = 0; i < 4; i++)
        #pragma unroll
        for (int j = 0; j < 4; j++)
            acc[i][j] = (f32x4){0.f, 0.f, 0.f, 0.f};

    int sw = l16 & 7;                               // read-side swizzle key

    auto issue = [&](int buf, int k0) {
        #pragma unroll
        for (int i = 0; i < 4; i++) {
            int row = st_row_base + i * 8;
            const bf16* ga = A  + (size_t)(bm0 + row) * K + k0 + st_col;
            const bf16* gb = BT + (size_t)(bn0 + row) * K + k0 + st_col;
            bf16* la = As + (size_t)buf * (128*64) + (size_t)(wave * 256 + i * 64) * 8;
            bf16* lb = Bs + (size_t)buf * (128*64) + (size_t)(wave * 256 + i * 64) * 8;
            async_cp16(ga, la);
            async_cp16(gb, lb);
        }
    };
    auto compute = [&](int buf) {
        const bf16* as = As + (size_t)buf * (128*64);
        const bf16* bs = Bs + (size_t)buf * (128*64);
        #pragma unroll
        for (int ks = 0; ks < 2; ks++) {
            bf16x8 af[4], bfr[4];
            #pragma unroll
            for (int mi = 0; mi < 4; mi++) {
                int row = wr*64 + mi*16 + l16;
                int kgs = (4*ks + quad) ^ sw;
                af[mi] = *(const bf16x8*)&as[row*64 + kgs*8];
            }
            #pragma unroll
            for (int ni = 0; ni < 4; ni++) {
                int row = wc*64 + ni*16 + l16;
                int kgs = (4*ks + quad) ^ sw;
                bfr[ni] = *(const bf16x8*)&bs[row*64 + kgs*8];
            }
            #pragma unroll
            for (int mi = 0; mi < 4; mi++)
                #pragma unroll
                for (int ni = 0; ni < 4; ni++)
                    acc[mi][ni] = __builtin_amdgcn_mfma_f32_16x16x32_bf16(af[mi], bfr[ni], acc[mi][ni], 0, 0, 0);
        }
    };

    if (DB) {
        int KT = K >> 6;
        issue(0, 0);
        for (int kt = 0; kt < KT; kt++) {
            int cur = kt & 1;
            if (kt + 1 < KT) { issue(cur ^ 1, (kt + 1) << 6); WAITCNT_VM(8); }
            else             { WAITCNT_VM(0); }
            __builtin_amdgcn_s_barrier();   // all waves' cur-tile data now in LDS
            compute(cur);
            __builtin_amdgcn_s_barrier();   // cur fully read; next iter may overwrite
        }
    } else {
        for (int k0 = 0; k0 < K; k0 += 64) {
            issue(0, k0);
            __syncthreads();
            compute(0);
            __syncthreads();
        }
    }

    // epilogue: D row = base + 4*quad + reg, col = base + l16 (m89-verified)
    #pragma unroll
    for (int mi = 0; mi < 4; mi++) {
        #pragma unroll
        for (int ni = 0; ni < 4; ni++) {
            int col = bn0 + wc*64 + ni*16 + l16;
            float bv = 0.f;
            if (bias) bv = (flags & GF_BIAS_EXT) ? ldf(bias, boff + col, f32m)
                                                 : (float)((const bf16*)bias)[col];
            #pragma unroll
            for (int r = 0; r < 4; r++) {
                int row = bm0 + wr*64 + mi*16 + quad*4 + r;
                float val = acc[mi][ni][r] + bv;
                if (flags & GF_GELU) val = 0.5f * val * (1.f + erff(val * 0.70710678118f));
                if (flags & GF_RES)  val += res[(size_t)row * N + col];
                size_t oidx = (size_t)row * N + col;
                if (flags & GF_OUTF32)      ((float*)outp)[oidx] = val;
                else if (flags & GF_OUTDYN) {
                    if (f32m) ((float*)outp)[oidx] = val;
                    else      ((bf16*)outp)[oidx]  = (bf16)val;
                }
                else                        ((bf16*)outp)[oidx]  = (bf16)val;
            }
        }
    }
}

// ---------------- paired flash attention ----------------------------------------
__device__ __forceinline__ void attn_qk_softmax(
    const bf16x8 qf[2], f32x4 Oacc[4], float mrow[4], float lrow[4],
    const bf16 (*Ks)[72], bf16 (*Ps)[72],
    int wave, int quad, int l16, int s0, int qt0, bool diag)
{
    f32x4 S[4];
    #pragma unroll
    for (int i = 0; i < 4; i++) S[i] = (f32x4){0.f, 0.f, 0.f, 0.f};
    #pragma unroll
    for (int ks = 0; ks < 2; ks++)
        #pragma unroll
        for (int ni = 0; ni < 4; ni++) {
            bf16x8 kf = *(const bf16x8*)&Ks[ni*16 + l16][ks*32 + quad*8];
            S[ni] = __builtin_amdgcn_mfma_f32_16x16x32_bf16(qf[ks], kf, S[ni], 0, 0, 0);
        }
    #pragma unroll
    for (int ni = 0; ni < 4; ni++)
        #pragma unroll
        for (int r = 0; r < 4; r++) {
            float sv = S[ni][r] * 0.125f;
            if (diag) {
                int scol = s0 + ni*16 + l16;
                int qr   = qt0 + wave*16 + quad*4 + r;
                if (scol > qr) sv = -1e30f;
            }
            S[ni][r] = sv;
        }
    #pragma unroll
    for (int r = 0; r < 4; r++) {
        float tm = fmaxf(fmaxf(S[0][r], S[1][r]), fmaxf(S[2][r], S[3][r]));
        #pragma unroll
        for (int off = 1; off <= 8; off <<= 1) tm = fmaxf(tm, __shfl_xor(tm, off));
        float mnew = fmaxf(mrow[r], tm);
        float alpha = expf(mrow[r] - mnew);
        mrow[r] = mnew;
        float rsum = 0.f;
        #pragma unroll
        for (int ni = 0; ni < 4; ni++) {
            float p = expf(S[ni][r] - mnew);
            S[ni][r] = p;
            rsum += p;
        }
        #pragma unroll
        for (int off = 1; off <= 8; off <<= 1) rsum += __shfl_xor(rsum, off);
        lrow[r] = lrow[r] * alpha + rsum;
        #pragma unroll
        for (int ni = 0; ni < 4; ni++) Oacc[ni][r] *= alpha;
        #pragma unroll
        for (int ni = 0; ni < 4; ni++)
            Ps[wave*16 + quad*4 + r][ni*16 + l16] = (bf16)S[ni][r];   // C->LDS
    }
}

__device__ __forceinline__ void attn_pv(
    f32x4 Oacc[4], const bf16 (*Ps)[72], const bf16 (*Vt)[72],
    int wave, int quad, int l16)
{
    #pragma unroll
    for (int ks = 0; ks < 2; ks++) {
        bf16x8 pf = *(const bf16x8*)&Ps[wave*16 + l16][ks*32 + quad*8];
        #pragma unroll
        for (int ni = 0; ni < 4; ni++) {
            bf16x8 vf = *(const bf16x8*)&Vt[ni*16 + l16][ks*32 + quad*8];
            Oacc[ni] = __builtin_amdgcn_mfma_f32_16x16x32_bf16(pf, vf, Oacc[ni], 0, 0, 0);
        }
    }
}

__global__ __launch_bounds__(256) void k_attn(const bf16* __restrict__ qkv, bf16* __restrict__ y)
{
    int xA = blockIdx.x;              // 0..7 (light strip)
    int xB = 15 - xA;                 // 8..15 (heavy strip)
    int qtA = xA * 64, qtB = xB * 64;
    int h = blockIdx.y, b = blockIdx.z;
    int tid = threadIdx.x, wave = tid >> 6, lane = tid & 63, quad = lane >> 4, l16 = lane & 15;

    const bf16* qb = qkv + (size_t)b * T_ * QKVN + h * 64;
    const bf16* kb = qb + E_;
    const bf16* vb = qb + 2 * E_;

    __shared__ __attribute__((aligned(16))) bf16 Ks[64][72];
    __shared__ __attribute__((aligned(16))) bf16 Vt[64][72];   // Vt[d][s]
    __shared__ __attribute__((aligned(16))) bf16 U1[64][72];   // Vs staging, then PsB
    __shared__ __attribute__((aligned(16))) bf16 PsA[64][72];

    bf16x8 qfA[2], qfB[2];
    {
        int qrA = qtA + wave * 16 + l16;
        int qrB = qtB + wave * 16 + l16;
        #pragma unroll
        for (int ks = 0; ks < 2; ks++) {
            qfA[ks] = *(const bf16x8*)(qb + (size_t)qrA * QKVN + ks*32 + quad*8);
            qfB[ks] = *(const bf16x8*)(qb + (size_t)qrB * QKVN + ks*32 + quad*8);
        }
    }

    f32x4 OA[4], OB[4];
    #pragma unroll
    for (int i = 0; i < 4; i++) { OA[i] = (f32x4){0.f,0.f,0.f,0.f}; OB[i] = (f32x4){0.f,0.f,0.f,0.f}; }
    float mA[4] = {-3.0e38f,-3.0e38f,-3.0e38f,-3.0e38f}, lA[4] = {0.f,0.f,0.f,0.f};
    float mB[4] = {-3.0e38f,-3.0e38f,-3.0e38f,-3.0e38f}, lB[4] = {0.f,0.f,0.f,0.f};

    for (int st = 0; st <= xB; st++) {
        int s0 = st * 64;
        bool doA = (st <= xA);
        #pragma unroll
        for (int i = 0; i < 2; i++) {
            int li = i * 256 + tid;
            int row = li >> 3;
            int col = (li & 7) * 8;
            *(bf16x8*)&Ks[row][col] = *(const bf16x8*)(kb + (size_t)(s0 + row) * QKVN + col);
            *(bf16x8*)&U1[row][col] = *(const bf16x8*)(vb + (size_t)(s0 + row) * QKVN + col);
        }
        __syncthreads();
        // two-step transpose U1(Vs) -> Vt: scalar reads (dword-broadcast), b128 writes
        {
            int d = tid & 63;
            #pragma unroll
            for (int ii = 0; ii < 2; ii++) {
                int sb = (tid >> 6) * 2 + ii;      // 0..7
                bf16x8 tv;
                #pragma unroll
                for (int j = 0; j < 8; j++) tv[j] = U1[sb*8 + j][d];
                *(bf16x8*)&Vt[d][sb*8] = tv;
            }
        }
        __syncthreads();                            // Vs dead; U1 becomes PsB
        attn_qk_softmax(qfB, OB, mB, lB, Ks, U1,  wave, quad, l16, s0, qtB, st == xB);
        if (doA)
            attn_qk_softmax(qfA, OA, mA, lA, Ks, PsA, wave, quad, l16, s0, qtA, st == xA);
        __syncthreads();                            // P visible across lanes
        attn_pv(OB, U1,  Vt, wave, quad, l16);
        if (doA) attn_pv(OA, PsA, Vt, wave, quad, l16);
        __syncthreads();                            // before restaging
    }

    #pragma unroll
    for (int ni = 0; ni < 4; ni++)
        #pragma unroll
        for (int r = 0; r < 4; r++) {
            int rowB = qtB + wave*16 + quad*4 + r;
            int rowA = qtA + wave*16 + quad*4 + r;
            y[(size_t)(b * T_ + rowB) * E_ + h*64 + ni*16 + l16] = (bf16)(OB[ni][r] / lB[r]);
            y[(size_t)(b * T_ + rowA) * E_ + h*64 + ni*16 + l16] = (bf16)(OA[ni][r] / lA[r]);
        }
}

// ---------------- host-side orchestration ----------------
extern "C" void kernel_launch(void* const* d_in, const int* in_sizes, int n_in,
                              void* d_out, int out_size, void* d_ws, size_t ws_size,
                              hipStream_t stream)
{
    const void* idx     = d_in[0];
    const void* tok_emb = d_in[1];
    const void* pos_emb = d_in[2];
    const void* ln1_w   = d_in[3];
    const void* ln1_b   = d_in[4];
    const void* Wq      = d_in[5];
    const void* bq      = d_in[6];
    const void* Wk      = d_in[7];
    const void* bk      = d_in[8];
    const void* Wv      = d_in[9];
    const void* bv      = d_in[10];
    const void* Wp      = d_in[11];
    const void* bp      = d_in[12];
    const void* ln2_w   = d_in[13];
    const void* ln2_b   = d_in[14];
    const void* W1      = d_in[15];
    const void* b1      = d_in[16];
    const void* W2      = d_in[17];
    const void* b2      = d_in[18];
    const void* lnf_w   = d_in[19];
    const void* lnf_b   = d_in[20];
    const void* lm_head = d_in[21];

    char* base = (char*)d_ws;
    size_t off = 0;
    auto nxt = [&](size_t bytes) -> void* {
        void* p = base + off;
        off += (bytes + 255) & ~(size_t)255;
        return p;
    };
    int*   dm   = (int*)  nxt(256);                     // dtype-mode flags
    float* x    = (float*)nxt((size_t)M_ * E_ * 4);     // fp32 residual stream
    bf16*  h    = (bf16*) nxt((size_t)M_ * E_ * 2);     // LN output
    bf16*  qkv  = (bf16*) nxt((size_t)M_ * QKVN * 2);
    bf16*  yb   = (bf16*) nxt((size_t)M_ * E_ * 2);     // attention output
    bf16*  mbuf = (bf16*) nxt((size_t)M_ * E4_ * 2);    // MLP intermediate
    bf16*  wt   = (bf16*) nxt((size_t)E4_ * E_ * 2);    // transposed-weight scratch (reused)
    bf16*  bcat = (bf16*) nxt((size_t)QKVN * 2);
    (void)ws_size; (void)in_sizes; (void)n_in; (void)out_size;

    k_probe<<<1, 256, 0, stream>>>(tok_emb, idx, dm);
    k_embed<<<M_, 256, 0, stream>>>(idx, tok_emb, pos_emb, x, dm);

    for (int l = 0; l < L_; l++) {
        size_t woE  = (size_t)l * E_ * E_;     // element offset into [L,E,E]
        size_t voE  = (size_t)l * E_;          // element offset into [L,E]
        size_t woW1 = (size_t)l * E_ * E4_;    // element offset into [L,E,4E]
        size_t voE4 = (size_t)l * E4_;         // element offset into [L,4E]

        k_ln<<<M_, 256, 0, stream>>>(x, ln1_w, ln1_b, voE, h, dm);

        k_transpose<<<dim3(E_/32, E_/32), 256, 0, stream>>>(Wq, woE, wt,                   E_, E_, dm);
        k_transpose<<<dim3(E_/32, E_/32), 256, 0, stream>>>(Wk, woE, wt + (size_t)E_*E_,   E_, E_, dm);
        k_transpose<<<dim3(E_/32, E_/32), 256, 0, stream>>>(Wv, woE, wt + (size_t)2*E_*E_, E_, E_, dm);
        k_cat3<<<QKVN/256, 256, 0, stream>>>(bq, bk, bv, voE, bcat, dm);
        k_gemm_t<false><<<dim3(QKVN/128, M_/128), 256, 0, stream>>>(h, wt, bcat, 0, nullptr, qkv, M_, QKVN, E_, 0, dm);

        k_attn<<<dim3(8, H_, B_), 256, 0, stream>>>(qkv, yb);

        k_transpose<<<dim3(E_/32, E_/32), 256, 0, stream>>>(Wp, woE, wt, E_, E_, dm);
        k_gemm_t<true><<<dim3(E_/128, M_/128), 256, 0, stream>>>(yb, wt, bp, voE, x, x, M_, E_, E_, GF_RES | GF_OUTF32 | GF_BIAS_EXT, dm);

        k_ln<<<M_, 256, 0, stream>>>(x, ln2_w, ln2_b, voE, h, dm);

        k_transpose<<<dim3(E_/32, E4_/32), 256, 0, stream>>>(W1, woW1, wt, E_, E4_, dm);
        k_gemm_t<false><<<dim3(E4_/128, M_/128), 256, 0, stream>>>(h, wt, b1, voE4, nullptr, mbuf, M_, E4_, E_, GF_GELU | GF_BIAS_EXT, dm);

        k_transpose<<<dim3(E4_/32, E_/32), 256, 0, stream>>>(W2, woW1, wt, E4_, E_, dm);
        k_gemm_t<true><<<dim3(E_/128, M_/128), 256, 0, stream>>>(mbuf, wt, b2, voE, x, x, M_, E_, E4_, GF_RES | GF_OUTF32 | GF_BIAS_EXT, dm);
    }

    k_ln<<<M_, 256, 0, stream>>>(x, lnf_w, lnf_b, 0, h, dm);
    k_transpose<<<dim3(E_/32, V_/32), 256, 0, stream>>>(lm_head, 0, wt, E_, V_, dm);
    k_gemm_t<true><<<dim3(V_/128, M_/128), 256, 0, stream>>>(h, wt, nullptr, 0, nullptr, d_out, M_, V_, E_, GF_OUTDYN, dm);
}

// Round 7
// 1823.444 us; speedup vs baseline: 3.1186x; 1.0339x over previous
//
#include <hip/hip_runtime.h>

#define L_ 6
#define E_ 768
#define H_ 12
#define T_ 1024
#define B_ 4
#define V_ 256
#define M_ (B_*T_)      // 4096 tokens
#define E4_ (4*E_)      // 3072
#define QKVN (3*E_)     // 2304

typedef __bf16 bf16;
typedef __bf16 bf16x8 __attribute__((ext_vector_type(8)));
typedef float f32x4 __attribute__((ext_vector_type(4)));

#define GF_GELU     1
#define GF_BIAS_EXT 16
#define GF_ATOMIC   32

// dual-mode scalar load of a "float" input that may be fp32 or bf16
__device__ __forceinline__ float ldf(const void* p, size_t i, int f32m) {
    return f32m ? ((const float*)p)[i] : (float)((const bf16*)p)[i];
}

// async global->LDS, 16B per lane; LDS dest = wave-uniform base + lane*16 (m97/m104)
__device__ __forceinline__ void async_cp16(const void* g, void* l) {
    __builtin_amdgcn_global_load_lds(
        (__attribute__((address_space(1))) void*)g,
        (__attribute__((address_space(3))) void*)l, 16, 0, 0);
}

// ---------------- dtype probe: dm[0]=inputs-are-fp32, dm[1]=idx-is-int64 --------
__global__ __launch_bounds__(256) void k_probe(const void* __restrict__ tok,
    const void* __restrict__ idxp, int* __restrict__ dm)
{
    __shared__ int sc1, sc2;
    if (threadIdx.x == 0) { sc1 = 0; sc2 = 0; }
    __syncthreads();
    const bf16* tb = (const bf16*)tok;
    int c1 = 0;
    for (int i = threadIdx.x; i < 4096; i += 256) {
        float v = (float)tb[2 * i];
        if (!(fabsf(v) < 100.f)) c1++;          // NaN lands here too
    }
    const int* ip = (const int*)idxp;
    int c2 = 0;
    for (int i = threadIdx.x; i < 1024; i += 256)
        if (ip[2 * i + 1] != 0) c2++;
    atomicAdd(&sc1, c1);
    atomicAdd(&sc2, c2);
    __syncthreads();
    if (threadIdx.x == 0) { dm[0] = (sc1 > 400) ? 1 : 0; dm[1] = (sc2 < 100) ? 1 : 0; }
}

// ---------------- embedding: x = tok_emb[idx] + pos_emb ----------------
__global__ __launch_bounds__(256) void k_embed(const void* __restrict__ idxp,
    const void* __restrict__ tok, const void* __restrict__ pos,
    float* __restrict__ x, const int* __restrict__ dm)
{
    int f32m = dm[0], i64m = dm[1];
    int bt = blockIdx.x;
    int t  = bt & (T_ - 1);
    int id = i64m ? ((const int*)idxp)[2 * bt] : ((const int*)idxp)[bt]; // LE low word
    float* xo = x + (size_t)bt * E_;
    for (int e = threadIdx.x; e < E_; e += 256)
        xo[e] = ldf(tok, (size_t)id * E_ + e, f32m) + ldf(pos, (size_t)t * E_ + e, f32m);
}

// ---------------- layernorm: fp32 x -> bf16 out (w,b external, +elem offset) ----
__global__ __launch_bounds__(256) void k_ln(const float* __restrict__ x,
    const void* __restrict__ w, const void* __restrict__ b, size_t wboff,
    bf16* __restrict__ out, const int* __restrict__ dm)
{
    int f32m = dm[0];
    int row = blockIdx.x;
    int tid = threadIdx.x;
    const float* xr = x + (size_t)row * E_;
    float v0 = xr[tid], v1 = xr[tid + 256], v2 = xr[tid + 512];
    float s  = v0 + v1 + v2;
    float s2 = v0*v0 + v1*v1 + v2*v2;
    for (int off = 32; off; off >>= 1) {
        s  += __shfl_xor(s,  off);
        s2 += __shfl_xor(s2, off);
    }
    __shared__ float ls[4], ls2[4];
    int wave = tid >> 6;
    if ((tid & 63) == 0) { ls[wave] = s; ls2[wave] = s2; }
    __syncthreads();
    s  = ls[0] + ls[1] + ls[2] + ls[3];
    s2 = ls2[0] + ls2[1] + ls2[2] + ls2[3];
    float mu  = s * (1.0f / E_);
    float var = s2 * (1.0f / E_) - mu * mu;
    float rs  = rsqrtf(var + 1e-5f);
    bf16* o = out + (size_t)row * E_;
    o[tid]       = (bf16)(((v0 - mu) * rs) * ldf(w, wboff + tid,       f32m) + ldf(b, wboff + tid,       f32m));
    o[tid + 256] = (bf16)(((v1 - mu) * rs) * ldf(w, wboff + tid + 256, f32m) + ldf(b, wboff + tid + 256, f32m));
    o[tid + 512] = (bf16)(((v2 - mu) * rs) * ldf(w, wboff + tid + 512, f32m) + ldf(b, wboff + tid + 512, f32m));
}

// ---------------- transpose external weight (+elem offset) -> canonical bf16 ----
__global__ __launch_bounds__(256) void k_transpose(const void* __restrict__ in, size_t inoff,
    bf16* __restrict__ out, int R, int C, const int* __restrict__ dm)
{
    int f32m = dm[0];
    __shared__ bf16 tile[32][33];
    int r0 = blockIdx.x * 32, c0 = blockIdx.y * 32;
    int tx = threadIdx.x & 31, ty = threadIdx.x >> 5;   // 32 x 8
    #pragma unroll
    for (int i = 0; i < 4; i++)
        tile[ty + 8*i][tx] = (bf16)ldf(in, inoff + (size_t)(r0 + ty + 8*i) * C + (c0 + tx), f32m);
    __syncthreads();
    #pragma unroll
    for (int i = 0; i < 4; i++)
        out[(size_t)(c0 + ty + 8*i) * R + (r0 + tx)] = tile[tx][ty + 8*i];
}

// fused Wq/Wk/Wv transpose: blockIdx.z selects source; out stride R*C per z
__global__ __launch_bounds__(256) void k_transpose3(const void* __restrict__ a,
    const void* __restrict__ b, const void* __restrict__ c, size_t inoff,
    bf16* __restrict__ out, int R, int C, const int* __restrict__ dm)
{
    int f32m = dm[0];
    const void* in = (blockIdx.z == 0) ? a : ((blockIdx.z == 1) ? b : c);
    bf16* o = out + (size_t)blockIdx.z * R * C;
    __shared__ bf16 tile[32][33];
    int r0 = blockIdx.x * 32, c0 = blockIdx.y * 32;
    int tx = threadIdx.x & 31, ty = threadIdx.x >> 5;
    #pragma unroll
    for (int i = 0; i < 4; i++)
        tile[ty + 8*i][tx] = (bf16)ldf(in, inoff + (size_t)(r0 + ty + 8*i) * C + (c0 + tx), f32m);
    __syncthreads();
    #pragma unroll
    for (int i = 0; i < 4; i++)
        o[(size_t)(c0 + ty + 8*i) * R + (r0 + tx)] = tile[tx][ty + 8*i];
}

// ---------------- concat 3 external bias vectors (+elem offset) -> bf16 ---------
__global__ __launch_bounds__(256) void k_cat3(const void* __restrict__ a,
    const void* __restrict__ b, const void* __restrict__ c, size_t voff,
    bf16* __restrict__ o, const int* __restrict__ dm)
{
    int f32m = dm[0];
    int i = blockIdx.x * 256 + threadIdx.x;   // grid covers QKVN exactly
    float v = (i < E_) ? ldf(a, voff + i, f32m)
            : ((i < 2*E_) ? ldf(b, voff + i - E_, f32m) : ldf(c, voff + i - 2*E_, f32m));
    o[i] = (bf16)v;
}

// ---------------- zero fp32 buffer ----------------
__global__ __launch_bounds__(256) void k_zero(float* __restrict__ p) {
    ((f32x4*)p)[blockIdx.x * 256 + threadIdx.x] = (f32x4){0.f, 0.f, 0.f, 0.f};
}

// ---------------- cast fp32 scratch -> output dtype ----------------
__global__ __launch_bounds__(256) void k_cast(const float* __restrict__ in,
    void* __restrict__ out, const int* __restrict__ dm)
{
    int i = blockIdx.x * 256 + threadIdx.x;
    float v = in[i];
    if (dm[0]) ((float*)out)[i] = v;
    else       ((bf16*)out)[i]  = (bf16)v;
}

// ---------------- GEMM: C[M,N] = A[M,K] @ BT[N,K]^T + bias -----------------------
// 128x128 tile, BK=64, 4 waves (2x2). Unpadded LDS, global_load_lds width=16, XOR
// swizzle in staging source address. Split-K via gridDim.z: each z-slice computes
// K/gridDim.z and (GF_ATOMIC) atomicAdds fp32 partials into outp (bias from z==0
// only). Rationale: small-N GEMMs at 192 blocks ran 1 block/CU and hit the ~11
// B/cyc/CU single-block vmem service ceiling; split-K restores 3 blocks/CU overlap.
__global__ __launch_bounds__(256) void k_gemm(const bf16* __restrict__ A,
    const bf16* __restrict__ BT, const void* __restrict__ bias, size_t boff,
    void* __restrict__ outp, int M, int N, int K, int flags, const int* __restrict__ dm)
{
    int f32m = dm[0];
    __shared__ __attribute__((aligned(16))) bf16 As[128 * 64];
    __shared__ __attribute__((aligned(16))) bf16 Bs[128 * 64];
    int tid = threadIdx.x;
    int bn0 = blockIdx.x * 128, bm0 = blockIdx.y * 128;
    int kz = blockIdx.z;
    int Ks = K / gridDim.z;
    int kbeg = kz * Ks, kend = kbeg + Ks;
    int wave = tid >> 6, lane = tid & 63, quad = lane >> 4, l16 = lane & 15;
    int wr = wave >> 1, wc = wave & 1;

    int st_col = 8 * ((lane & 7) ^ (lane >> 3));
    int st_row_base = wave * 32 + (lane >> 3);      // + i*8

    f32x4 acc[4][4];
    #pragma unroll
    for (int i = 0; i < 4; i++)
        #pragma unroll
        for (int j = 0; j < 4; j++)
            acc[i][j] = (f32x4){0.f, 0.f, 0.f, 0.f};

    int sw = l16 & 7;                               // read-side swizzle key
    for (int k0 = kbeg; k0 < kend; k0 += 64) {
        #pragma unroll
        for (int i = 0; i < 4; i++) {
            int row = st_row_base + i * 8;
            const bf16* ga = A  + (size_t)(bm0 + row) * K + k0 + st_col;
            const bf16* gb = BT + (size_t)(bn0 + row) * K + k0 + st_col;
            bf16* la = As + (size_t)(wave * 256 + i * 64) * 8;
            bf16* lb = Bs + (size_t)(wave * 256 + i * 64) * 8;
            async_cp16(ga, la);
            async_cp16(gb, lb);
        }
        __syncthreads();
        #pragma unroll
        for (int ks = 0; ks < 2; ks++) {
            bf16x8 af[4], bfr[4];
            #pragma unroll
            for (int mi = 0; mi < 4; mi++) {
                int row = wr*64 + mi*16 + l16;
                int kgs = (4*ks + quad) ^ sw;
                af[mi] = *(const bf16x8*)&As[row*64 + kgs*8];
            }
            #pragma unroll
            for (int ni = 0; ni < 4; ni++) {
                int row = wc*64 + ni*16 + l16;
                int kgs = (4*ks + quad) ^ sw;
                bfr[ni] = *(const bf16x8*)&Bs[row*64 + kgs*8];
            }
            #pragma unroll
            for (int mi = 0; mi < 4; mi++)
                #pragma unroll
                for (int ni = 0; ni < 4; ni++)
                    acc[mi][ni] = __builtin_amdgcn_mfma_f32_16x16x32_bf16(af[mi], bfr[ni], acc[mi][ni], 0, 0, 0);
        }
        __syncthreads();
    }

    // epilogue: D row = base + 4*quad + reg, col = base + l16 (m89-verified)
    #pragma unroll
    for (int mi = 0; mi < 4; mi++) {
        #pragma unroll
        for (int ni = 0; ni < 4; ni++) {
            int col = bn0 + wc*64 + ni*16 + l16;
            float bv = 0.f;
            if (bias && (!(flags & GF_ATOMIC) || kz == 0))
                bv = (flags & GF_BIAS_EXT) ? ldf(bias, boff + col, f32m)
                                           : (float)((const bf16*)bias)[col];
            #pragma unroll
            for (int r = 0; r < 4; r++) {
                int row = bm0 + wr*64 + mi*16 + quad*4 + r;
                float val = acc[mi][ni][r] + bv;
                if (flags & GF_GELU) val = 0.5f * val * (1.f + erff(val * 0.70710678118f));
                size_t oidx = (size_t)row * N + col;
                if (flags & GF_ATOMIC) atomicAdd(&((float*)outp)[oidx], val);
                else                   ((bf16*)outp)[oidx] = (bf16)val;
            }
        }
    }
}

// ---------------- paired flash attention ----------------------------------------
__device__ __forceinline__ void attn_qk_softmax(
    const bf16x8 qf[2], f32x4 Oacc[4], float mrow[4], float lrow[4],
    const bf16 (*Ks)[72], bf16 (*Ps)[72],
    int wave, int quad, int l16, int s0, int qt0, bool diag)
{
    f32x4 S[4];
    #pragma unroll
    for (int i = 0; i < 4; i++) S[i] = (f32x4){0.f, 0.f, 0.f, 0.f};
    #pragma unroll
    for (int ks = 0; ks < 2; ks++)
        #pragma unroll
        for (int ni = 0; ni < 4; ni++) {
            bf16x8 kf = *(const bf16x8*)&Ks[ni*16 + l16][ks*32 + quad*8];
            S[ni] = __builtin_amdgcn_mfma_f32_16x16x32_bf16(qf[ks], kf, S[ni], 0, 0, 0);
        }
    #pragma unroll
    for (int ni = 0; ni < 4; ni++)
        #pragma unroll
        for (int r = 0; r < 4; r++) {
            float sv = S[ni][r] * 0.125f;
            if (diag) {
                int scol = s0 + ni*16 + l16;
                int qr   = qt0 + wave*16 + quad*4 + r;
                if (scol > qr) sv = -1e30f;
            }
            S[ni][r] = sv;
        }
    #pragma unroll
    for (int r = 0; r < 4; r++) {
        float tm = fmaxf(fmaxf(S[0][r], S[1][r]), fmaxf(S[2][r], S[3][r]));
        #pragma unroll
        for (int off = 1; off <= 8; off <<= 1) tm = fmaxf(tm, __shfl_xor(tm, off));
        float mnew = fmaxf(mrow[r], tm);
        float alpha = expf(mrow[r] - mnew);
        mrow[r] = mnew;
        float rsum = 0.f;
        #pragma unroll
        for (int ni = 0; ni < 4; ni++) {
            float p = expf(S[ni][r] - mnew);
            S[ni][r] = p;
            rsum += p;
        }
        #pragma unroll
        for (int off = 1; off <= 8; off <<= 1) rsum += __shfl_xor(rsum, off);
        lrow[r] = lrow[r] * alpha + rsum;
        #pragma unroll
        for (int ni = 0; ni < 4; ni++) Oacc[ni][r] *= alpha;
        #pragma unroll
        for (int ni = 0; ni < 4; ni++)
            Ps[wave*16 + quad*4 + r][ni*16 + l16] = (bf16)S[ni][r];   // C->LDS
    }
}

__device__ __forceinline__ void attn_pv(
    f32x4 Oacc[4], const bf16 (*Ps)[72], const bf16 (*Vt)[72],
    int wave, int quad, int l16)
{
    #pragma unroll
    for (int ks = 0; ks < 2; ks++) {
        bf16x8 pf = *(const bf16x8*)&Ps[wave*16 + l16][ks*32 + quad*8];
        #pragma unroll
        for (int ni = 0; ni < 4; ni++) {
            bf16x8 vf = *(const bf16x8*)&Vt[ni*16 + l16][ks*32 + quad*8];
            Oacc[ni] = __builtin_amdgcn_mfma_f32_16x16x32_bf16(pf, vf, Oacc[ni], 0, 0, 0);
        }
    }
}

__global__ __launch_bounds__(256) void k_attn(const bf16* __restrict__ qkv, bf16* __restrict__ y)
{
    int xA = blockIdx.x;              // 0..7 (light strip)
    int xB = 15 - xA;                 // 8..15 (heavy strip)
    int qtA = xA * 64, qtB = xB * 64;
    int h = blockIdx.y, b = blockIdx.z;
    int tid = threadIdx.x, wave = tid >> 6, lane = tid & 63, quad = lane >> 4, l16 = lane & 15;

    const bf16* qb = qkv + (size_t)b * T_ * QKVN + h * 64;
    const bf16* kb = qb + E_;
    const bf16* vb = qb + 2 * E_;

    __shared__ __attribute__((aligned(16))) bf16 Ks[64][72];
    __shared__ __attribute__((aligned(16))) bf16 Vt[64][72];   // Vt[d][s]
    __shared__ __attribute__((aligned(16))) bf16 U1[64][72];   // Vs staging, then PsB
    __shared__ __attribute__((aligned(16))) bf16 PsA[64][72];

    bf16x8 qfA[2], qfB[2];
    {
        int qrA = qtA + wave * 16 + l16;
        int qrB = qtB + wave * 16 + l16;
        #pragma unroll
        for (int ks = 0; ks < 2; ks++) {
            qfA[ks] = *(const bf16x8*)(qb + (size_t)qrA * QKVN + ks*32 + quad*8);
            qfB[ks] = *(const bf16x8*)(qb + (size_t)qrB * QKVN + ks*32 + quad*8);
        }
    }

    f32x4 OA[4], OB[4];
    #pragma unroll
    for (int i = 0; i < 4; i++) { OA[i] = (f32x4){0.f,0.f,0.f,0.f}; OB[i] = (f32x4){0.f,0.f,0.f,0.f}; }
    float mA[4] = {-3.0e38f,-3.0e38f,-3.0e38f,-3.0e38f}, lA[4] = {0.f,0.f,0.f,0.f};
    float mB[4] = {-3.0e38f,-3.0e38f,-3.0e38f,-3.0e38f}, lB[4] = {0.f,0.f,0.f,0.f};

    for (int st = 0; st <= xB; st++) {
        int s0 = st * 64;
        bool doA = (st <= xA);
        #pragma unroll
        for (int i = 0; i < 2; i++) {
            int li = i * 256 + tid;
            int row = li >> 3;
            int col = (li & 7) * 8;
            *(bf16x8*)&Ks[row][col] = *(const bf16x8*)(kb + (size_t)(s0 + row) * QKVN + col);
            *(bf16x8*)&U1[row][col] = *(const bf16x8*)(vb + (size_t)(s0 + row) * QKVN + col);
        }
        __syncthreads();
        // two-step transpose U1(Vs) -> Vt: scalar reads (dword-broadcast), b128 writes
        {
            int d = tid & 63;
            #pragma unroll
            for (int ii = 0; ii < 2; ii++) {
                int sb = (tid >> 6) * 2 + ii;      // 0..7
                bf16x8 tv;
                #pragma unroll
                for (int j = 0; j < 8; j++) tv[j] = U1[sb*8 + j][d];
                *(bf16x8*)&Vt[d][sb*8] = tv;
            }
        }
        __syncthreads();                            // Vs dead; U1 becomes PsB
        attn_qk_softmax(qfB, OB, mB, lB, Ks, U1,  wave, quad, l16, s0, qtB, st == xB);
        if (doA)
            attn_qk_softmax(qfA, OA, mA, lA, Ks, PsA, wave, quad, l16, s0, qtA, st == xA);
        __syncthreads();                            // P visible across lanes
        attn_pv(OB, U1,  Vt, wave, quad, l16);
        if (doA) attn_pv(OA, PsA, Vt, wave, quad, l16);
        __syncthreads();                            // before restaging
    }

    #pragma unroll
    for (int ni = 0; ni < 4; ni++)
        #pragma unroll
        for (int r = 0; r < 4; r++) {
            int rowB = qtB + wave*16 + quad*4 + r;
            int rowA = qtA + wave*16 + quad*4 + r;
            y[(size_t)(b * T_ + rowB) * E_ + h*64 + ni*16 + l16] = (bf16)(OB[ni][r] / lB[r]);
            y[(size_t)(b * T_ + rowA) * E_ + h*64 + ni*16 + l16] = (bf16)(OA[ni][r] / lA[r]);
        }
}

// ---------------- host-side orchestration ----------------
extern "C" void kernel_launch(void* const* d_in, const int* in_sizes, int n_in,
                              void* d_out, int out_size, void* d_ws, size_t ws_size,
                              hipStream_t stream)
{
    const void* idx     = d_in[0];
    const void* tok_emb = d_in[1];
    const void* pos_emb = d_in[2];
    const void* ln1_w   = d_in[3];
    const void* ln1_b   = d_in[4];
    const void* Wq      = d_in[5];
    const void* bq      = d_in[6];
    const void* Wk      = d_in[7];
    const void* bk      = d_in[8];
    const void* Wv      = d_in[9];
    const void* bv      = d_in[10];
    const void* Wp      = d_in[11];
    const void* bp      = d_in[12];
    const void* ln2_w   = d_in[13];
    const void* ln2_b   = d_in[14];
    const void* W1      = d_in[15];
    const void* b1      = d_in[16];
    const void* W2      = d_in[17];
    const void* b2      = d_in[18];
    const void* lnf_w   = d_in[19];
    const void* lnf_b   = d_in[20];
    const void* lm_head = d_in[21];

    char* base = (char*)d_ws;
    size_t off = 0;
    auto nxt = [&](size_t bytes) -> void* {
        void* p = base + off;
        off += (bytes + 255) & ~(size_t)255;
        return p;
    };
    int*   dm   = (int*)  nxt(256);                     // dtype-mode flags
    float* x    = (float*)nxt((size_t)M_ * E_ * 4);     // fp32 residual stream
    bf16*  h    = (bf16*) nxt((size_t)M_ * E_ * 2);     // LN output
    bf16*  qkv  = (bf16*) nxt((size_t)M_ * QKVN * 2);
    bf16*  yb   = (bf16*) nxt((size_t)M_ * E_ * 2);     // attention output
    bf16*  mbuf = (bf16*) nxt((size_t)M_ * E4_ * 2);    // MLP intermediate
    bf16*  wt   = (bf16*) nxt((size_t)E4_ * E_ * 2);    // transposed-weight scratch (reused)
    bf16*  bcat = (bf16*) nxt((size_t)QKVN * 2);
    float* xl   = (float*)nxt((size_t)M_ * V_ * 4);     // lm_head fp32 accumulator
    (void)ws_size; (void)in_sizes; (void)n_in; (void)out_size;

    k_probe<<<1, 256, 0, stream>>>(tok_emb, idx, dm);
    k_embed<<<M_, 256, 0, stream>>>(idx, tok_emb, pos_emb, x, dm);

    for (int l = 0; l < L_; l++) {
        size_t woE  = (size_t)l * E_ * E_;     // element offset into [L,E,E]
        size_t voE  = (size_t)l * E_;          // element offset into [L,E]
        size_t woW1 = (size_t)l * E_ * E4_;    // element offset into [L,E,4E]
        size_t voE4 = (size_t)l * E4_;         // element offset into [L,4E]

        k_ln<<<M_, 256, 0, stream>>>(x, ln1_w, ln1_b, voE, h, dm);

        k_transpose3<<<dim3(E_/32, E_/32, 3), 256, 0, stream>>>(Wq, Wk, Wv, woE, wt, E_, E_, dm);
        k_cat3<<<QKVN/256, 256, 0, stream>>>(bq, bk, bv, voE, bcat, dm);
        k_gemm<<<dim3(QKVN/128, M_/128), 256, 0, stream>>>(h, wt, bcat, 0, qkv, M_, QKVN, E_, 0, dm);

        k_attn<<<dim3(8, H_, B_), 256, 0, stream>>>(qkv, yb);

        // proj: x += yb @ Wp^T + bp   (split-K=4, fp32 atomic into x)
        k_transpose<<<dim3(E_/32, E_/32), 256, 0, stream>>>(Wp, woE, wt, E_, E_, dm);
        k_gemm<<<dim3(E_/128, M_/128, 4), 256, 0, stream>>>(yb, wt, bp, voE, x, M_, E_, E_, GF_ATOMIC | GF_BIAS_EXT, dm);

        k_ln<<<M_, 256, 0, stream>>>(x, ln2_w, ln2_b, voE, h, dm);

        k_transpose<<<dim3(E_/32, E4_/32), 256, 0, stream>>>(W1, woW1, wt, E_, E4_, dm);
        k_gemm<<<dim3(E4_/128, M_/128), 256, 0, stream>>>(h, wt, b1, voE4, mbuf, M_, E4_, E_, GF_GELU | GF_BIAS_EXT, dm);

        // W2: x += mbuf @ W2^T + b2   (split-K=4, fp32 atomic into x)
        k_transpose<<<dim3(E4_/32, E_/32), 256, 0, stream>>>(W2, woW1, wt, E4_, E_, dm);
        k_gemm<<<dim3(E_/128, M_/128, 4), 256, 0, stream>>>(mbuf, wt, b2, voE, x, M_, E_, E4_, GF_ATOMIC | GF_BIAS_EXT, dm);
    }

    k_ln<<<M_, 256, 0, stream>>>(x, lnf_w, lnf_b, 0, h, dm);
    k_transpose<<<dim3(E_/32, V_/32), 256, 0, stream>>>(lm_head, 0, wt, E_, V_, dm);
    k_zero<<<(M_*V_)/1024, 256, 0, stream>>>(xl);
    k_gemm<<<dim3(V_/128, M_/128, 4), 256, 0, stream>>>(h, wt, nullptr, 0, xl, M_, V_, E_, GF_ATOMIC, dm);
    k_cast<<<(M_*V_)/256, 256, 0, stream>>>(xl, d_out, dm);
}